// Round 4
// baseline (171.789 us; speedup 1.0000x reference)
//
#include <hip/hip_runtime.h>

// pixelSNAIL causal attention, MI355X gfx950.
// B=32, N=1024, C=128, CM=256, fp32 in/out.
// softmax over FULL row, strict causal mask, then @V.
// R4: prep_kernel: coalesced global IO + LDS transpose (XOR-swizzled slots).
// R5: swapped QK^T (mfma(K,Q)) -> P lane-local; in-register P->A-frag via
//     cvt_pk_bf16 + permlane32/16_swap; K dbuf prefetched one tile ahead,
//     counted vmcnt.
// R6 (reverted): 32 rows/wave @ 1 block/CU -> 1 wave/SIMD, stalls exposed.
// R7: CM-split occupancy: each block owns 64 q-rows x ONE 128-col half of V.
//     Grid 32x16x2 = 1024 blocks; LDS = K dbuf 32KB + V-half single 8KB
//     = 40KB -> 4 blocks/CU = 4 waves/SIMD (2x R5 TLP). QK^T/softmax are
//     duplicated across the two halves (MFMA/VALU were <25% busy; TLP is
//     what's scarce). V(t) issued at top-of-tile, drained by the counted
//     vmcnt(4) with K(t+1) left in flight; V-half WAR protected by barrier2.

typedef __attribute__((ext_vector_type(8))) short short8;
typedef __attribute__((ext_vector_type(4))) float floatx4;

#define MFMA16(a, b, c) __builtin_amdgcn_mfma_f32_16x16x32_bf16((a), (b), (c), 0, 0, 0)

constexpr int N = 1024, C = 128, CM = 256, BATCH = 32;
constexpr int BM = 64;             // q rows per block (4 waves x 16 rows)
constexpr int BN = 32;             // keys per tile
constexpr int NT = N / BN;         // 32 tiles
constexpr int KFRAG = BN * C;      // 4096 bf16 per K tile (hi or lo)
constexpr int VFRAG = BN * CM;     // 8192 bf16 per V tile
constexpr int VHALF = VFRAG / 2;   // 4096 bf16 per V half-tile (128 cols)

__device__ __forceinline__ unsigned short f2bf(float x) {
    unsigned int u = __float_as_uint(x);
    u += 0x7fffu + ((u >> 16) & 1u);   // RNE
    return (unsigned short)(u >> 16);
}
__device__ __forceinline__ float bf2f(unsigned short h) {
    return __uint_as_float(((unsigned int)h) << 16);
}
__device__ __forceinline__ uint2 pack4(const unsigned short* s) {
    uint2 u;
    u.x = (unsigned)s[0] | ((unsigned)s[1] << 16);
    u.y = (unsigned)s[2] | ((unsigned)s[3] << 16);
    return u;
}
__device__ __forceinline__ void gl2lds16(const unsigned short* g, unsigned short* l) {
    __builtin_amdgcn_global_load_lds(
        (const __attribute__((address_space(1))) void*)g,
        (__attribute__((address_space(3))) void*)l, 16, 0, 0);
}

// ---------------- prepass: coalesced global IO, LDS transpose ----------------
// Output layouts (consumed by attn_kernel):
//  khi/klo chunk ch in [0,512):  rr=ch&15, qq=(ch>>4)&3, ks=(ch>>6)&3, t=ch>>8
//    khb[ch*8+j] = bf16hi(K[n0 + t*16 + rr][ks*32 + qq*8 + j])
//  vf chunk ch in [0,1024):      rr=ch&15, qq=(ch>>4)&3, ct=ch>>6
//    vfb[ch*8+j] = bf16(V[n0 + qq*8 + j][ct*16 + rr])
__global__ __launch_bounds__(256, 4)
void prep_kernel(const float* __restrict__ kg, const float* __restrict__ vg,
                 unsigned short* __restrict__ khi, unsigned short* __restrict__ klo,
                 unsigned short* __restrict__ vf)
{
    __shared__ __align__(16) unsigned short sKh[KFRAG];   // 8 KB
    __shared__ __align__(16) unsigned short sKl[KFRAG];   // 8 KB
    __shared__ __align__(16) unsigned short sV[VFRAG];    // 16 KB

    const int tid = threadIdx.x;
    const int l = tid & 63, w = tid >> 6;
    const int tile = blockIdx.x, bat = blockIdx.y;
    const int n0 = tile * BN;
    const float* kb = kg + ((size_t)bat * N + n0) * C;
    const float* vb = vg + ((size_t)bat * N + n0) * CM;

    // ---- K staging: contiguous float4 reads (1 KB/instr/wave) ----
#pragma unroll
    for (int it = 0; it < 4; ++it) {
        const int lin = tid + it * 256;
        const float4 x = *(const float4*)(kb + (size_t)lin * 4);
        const int cr = lin >> 1, h = lin & 1;
        const int slot = cr ^ ((cr >> 4) & 7);
        float xs[4] = {x.x, x.y, x.z, x.w};
        unsigned short hi[4], lo[4];
#pragma unroll
        for (int e = 0; e < 4; ++e) {
            unsigned short hb = f2bf(xs[e]);
            hi[e] = hb;
            lo[e] = f2bf(xs[e] - bf2f(hb));
        }
        *(uint2*)(&sKh[slot * 8 + h * 4]) = pack4(hi);
        *(uint2*)(&sKl[slot * 8 + h * 4]) = pack4(lo);
    }

    // ---- V staging: 4 contiguous row-segment float4 reads per group ----
#pragma unroll
    for (int g = 0; g < 2; ++g) {
        const int k0 = g * 16 + w * 4;
        float xa[4][4];   // [e][d] = V[k0+d][4l+e]
#pragma unroll
        for (int d = 0; d < 4; ++d) {
            const float4 t = *(const float4*)(vb + (size_t)(k0 + d) * CM + l * 4);
            xa[0][d] = t.x; xa[1][d] = t.y; xa[2][d] = t.z; xa[3][d] = t.w;
        }
        const int qq = k0 >> 3, j0 = k0 & 7;
#pragma unroll
        for (int e = 0; e < 4; ++e) {
            const int cm = l * 4 + e;
            const int ct = cm >> 4, rr = cm & 15;
            const int ch = ct * 64 + qq * 16 + rr;
            const int slot = ch ^ ((ch >> 6) & 15);
            unsigned short o[4];
#pragma unroll
            for (int d = 0; d < 4; ++d) o[d] = f2bf(xa[e][d]);
            *(uint2*)(&sV[slot * 8 + j0]) = pack4(o);
        }
    }

    __syncthreads();

    unsigned short* khb = khi + ((size_t)bat * NT + tile) * KFRAG;
    unsigned short* klb = klo + ((size_t)bat * NT + tile) * KFRAG;
    unsigned short* vfb = vf + ((size_t)bat * NT + tile) * VFRAG;

    // ---- K out: linear b128 LDS reads, coalesced 16 B/lane global stores ----
#pragma unroll
    for (int it = 0; it < 2; ++it) {
        const int oc = tid + it * 256;
        const int cr = ((oc & 15) + ((oc >> 8) << 4)) * 16 + ((oc >> 6) & 3) * 4 + ((oc >> 4) & 3);
        const int slot = cr ^ ((cr >> 4) & 7);
        *(uint4*)(khb + (size_t)oc * 8) = *(const uint4*)(&sKh[slot * 8]);
        *(uint4*)(klb + (size_t)oc * 8) = *(const uint4*)(&sKl[slot * 8]);
    }
    // ---- V out ----
#pragma unroll
    for (int it = 0; it < 4; ++it) {
        const int oc = tid + it * 256;
        const int slot = oc ^ ((oc >> 6) & 15);
        *(uint4*)(vfb + (size_t)oc * 8) = *(const uint4*)(&sV[slot * 8]);
    }
}

// ---------------- main attention kernel ----------------
__global__ __launch_bounds__(256, 4)
void attn_kernel(const float* __restrict__ qg, float* __restrict__ og,
                 const unsigned short* __restrict__ khi,
                 const unsigned short* __restrict__ klo,
                 const unsigned short* __restrict__ vf)
{
    __shared__ __align__(16) unsigned short sKhi[2][KFRAG];  // 16 KB dbuf
    __shared__ __align__(16) unsigned short sKlo[2][KFRAG];  // 16 KB dbuf
    __shared__ __align__(16) unsigned short sV[VHALF];       // 8 KB single (CM half)

    const int tid = threadIdx.x;
    const int w = tid >> 6, ln = tid & 63;
    const int r = ln & 15, qd = ln >> 4;
    const int bat = blockIdx.x;   // batch on x: linear%8 = bat%8 -> same XCD per batch
    const int qt = blockIdx.y;
    const int half = blockIdx.z;  // which 128-col half of CM this block owns
    const int q0 = qt * BM;

    const float* qb = qg + (size_t)bat * N * C;
    float* ob = og + (size_t)bat * N * CM;
    const unsigned short* khb = khi + (size_t)bat * NT * KFRAG;
    const unsigned short* klb = klo + (size_t)bat * NT * KFRAG;
    const unsigned short* vfb = vf + (size_t)bat * NT * VFRAG;

    // Q fragments for this wave's 16 rows (q0 + w*16 + r), hi/lo split
    short8 qhi[4], qlo[4];
    {
        const float* qr = qb + (size_t)(q0 + w * 16 + r) * C + qd * 8;
#pragma unroll
        for (int ks = 0; ks < 4; ++ks) {
            float4 a = *(const float4*)(qr + ks * 32);
            float4 b = *(const float4*)(qr + ks * 32 + 4);
            float xs[8] = {a.x, a.y, a.z, a.w, b.x, b.y, b.z, b.w};
            short8 h, l;
#pragma unroll
            for (int j = 0; j < 8; ++j) {
                unsigned short hb = f2bf(xs[j]);
                h[j] = (short)hb;
                l[j] = (short)f2bf(xs[j] - bf2f(hb));
            }
            qhi[ks] = h;
            qlo[ks] = l;
        }
    }

    floatx4 oacc[8];
#pragma unroll
    for (int ct = 0; ct < 8; ++ct) oacc[ct] = (floatx4){0.f, 0.f, 0.f, 0.f};
    float lsum = 0.f;                       // this lane's q-row partial denom
    const int qrow = q0 + w * 16 + r;       // swapped-QK^T: lane owns ONE q-row

    // prologue: prefetch K(0) into buffer 0 (4 loads/thread)
    gl2lds16(khb + (size_t)tid * 8,         &sKhi[0][tid * 8]);
    gl2lds16(khb + (size_t)(tid + 256) * 8, &sKhi[0][(tid + 256) * 8]);
    gl2lds16(klb + (size_t)tid * 8,         &sKlo[0][tid * 8]);
    gl2lds16(klb + (size_t)(tid + 256) * 8, &sKlo[0][(tid + 256) * 8]);

    for (int tile = 0; tile < NT; ++tile) {
        const bool pvt = (tile <= 2 * qt + 1);   // tile holds keys < some row in block
        const int cb = tile & 1;

        // issue V-half(t) (single buffer; PV readers of V(t-1) finished before
        // barrier2 of the previous iteration -> WAR safe).
        if (pvt) {
            const unsigned short* vs = vfb + (size_t)tile * VFRAG + (size_t)half * VHALF;
            gl2lds16(vs + (size_t)tid * 8,         &sV[tid * 8]);
            gl2lds16(vs + (size_t)(tid + 256) * 8, &sV[(tid + 256) * 8]);
        }
        // prefetch K(t+1) into the other K buffer; counted vmcnt drains
        // K(t)+V(t) while leaving exactly the 4 K(t+1) loads in flight.
        if (tile + 1 < NT) {
            const unsigned short* k1 = khb + (size_t)(tile + 1) * KFRAG;
            const unsigned short* l1 = klb + (size_t)(tile + 1) * KFRAG;
            unsigned short* dh = &sKhi[cb ^ 1][0];
            unsigned short* dl = &sKlo[cb ^ 1][0];
            gl2lds16(k1 + (size_t)tid * 8,         dh + tid * 8);
            gl2lds16(k1 + (size_t)(tid + 256) * 8, dh + (tid + 256) * 8);
            gl2lds16(l1 + (size_t)tid * 8,         dl + tid * 8);
            gl2lds16(l1 + (size_t)(tid + 256) * 8, dl + (tid + 256) * 8);
            asm volatile("s_waitcnt vmcnt(4)" ::: "memory");
        } else {
            asm volatile("s_waitcnt vmcnt(0)" ::: "memory");
        }
        asm volatile("s_barrier" ::: "memory");   // all waves' K(t)/V(t) staged

        // ---- swapped QK^T bf16x3: D[key][qrow], 3 independent chains ----
        float pk[8];
#pragma unroll
        for (int t = 0; t < 2; ++t) {
            floatx4 a0 = (floatx4){0.f, 0.f, 0.f, 0.f};
            floatx4 a1 = (floatx4){0.f, 0.f, 0.f, 0.f};
            floatx4 a2 = (floatx4){0.f, 0.f, 0.f, 0.f};
#pragma unroll
            for (int ks = 0; ks < 4; ++ks) {
                short8 bh = *(const short8*)(&sKhi[cb][(((t * 4 + ks) * 64) + ln) * 8]);
                short8 bl = *(const short8*)(&sKlo[cb][(((t * 4 + ks) * 64) + ln) * 8]);
                a0 = MFMA16(bh, qhi[ks], a0);     // A=K -> rows=keys, cols=qrows
                a1 = MFMA16(bh, qlo[ks], a1);
                a2 = MFMA16(bl, qhi[ks], a2);
            }
            const int kbase = tile * BN + t * 16 + qd * 4;
#pragma unroll
            for (int rg = 0; rg < 4; ++rg) {
                float s = a0[rg] + a1[rg] + a2[rg];
                float p = __expf(s - 40.0f);
                lsum += p;                                  // full-row denominator
                pk[t * 4 + rg] = (kbase + rg < qrow) ? p : 0.0f;  // strict causal
            }
        }

        // ---- PV over this block's CM half: P->A-frag in-register ----
        if (pvt) {
            unsigned int w0, w1, w2, w3;
            asm("v_cvt_pk_bf16_f32 %0, %1, %2" : "=v"(w0) : "v"(pk[0]), "v"(pk[1]));
            asm("v_cvt_pk_bf16_f32 %0, %1, %2" : "=v"(w1) : "v"(pk[2]), "v"(pk[3]));
            asm("v_cvt_pk_bf16_f32 %0, %1, %2" : "=v"(w2) : "v"(pk[4]), "v"(pk[5]));
            asm("v_cvt_pk_bf16_f32 %0, %1, %2" : "=v"(w3) : "v"(pk[6]), "v"(pk[7]));
            asm("v_permlane32_swap_b32 %0, %1" : "+v"(w0), "+v"(w2));
            asm("v_permlane16_swap_b32 %0, %1" : "+v"(w0), "+v"(w2));
            asm("v_permlane32_swap_b32 %0, %1" : "+v"(w1), "+v"(w3));
            asm("v_permlane16_swap_b32 %0, %1" : "+v"(w1), "+v"(w3));
            uint4 apu = make_uint4(w0, w1, w2, w3);   // keys (0,1)(2,3)(4,5)(6,7)+8qd
            short8 ap = *(const short8*)&apu;
#pragma unroll
            for (int ct = 0; ct < 8; ++ct) {
                short8 bv = *(const short8*)(&sV[(ct * 64 + ln) * 8]);
                oacc[ct] = MFMA16(ap, bv, oacc[ct]);
            }
        }
        asm volatile("s_barrier" ::: "memory");   // readers done before next overwrite
    }

    // ---- denominator: reduce across the 4 qd groups (lane owns row r) ----
    float vtot = lsum;
    vtot += __shfl_xor(vtot, 16);
    vtot += __shfl_xor(vtot, 32);
    // vtot = full denom for row (q0 + w*16 + r) on every lane

    // ---- divide + store (this block's 128-col half) ----
#pragma unroll
    for (int rg = 0; rg < 4; ++rg) {
        float inv = 1.0f / __shfl(vtot, qd * 4 + rg);   // lane qd*4+rg has row qd*4+rg
        float* orow = ob + (size_t)(q0 + w * 16 + qd * 4 + rg) * CM;
#pragma unroll
        for (int ct = 0; ct < 8; ++ct)
            orow[(half * 8 + ct) * 16 + r] = oacc[ct][rg] * inv;
    }
}

extern "C" void kernel_launch(void* const* d_in, const int* in_sizes, int n_in,
                              void* d_out, int out_size, void* d_ws, size_t ws_size,
                              hipStream_t stream) {
    const float* q = (const float*)d_in[0];
    const float* k = (const float*)d_in[1];
    const float* v = (const float*)d_in[2];
    float* o = (float*)d_out;
    (void)n_in; (void)in_sizes; (void)out_size; (void)ws_size;

    unsigned short* khi = (unsigned short*)d_ws;                       // 8 MB
    unsigned short* klo = khi + (size_t)BATCH * NT * KFRAG;            // 8 MB
    unsigned short* vf  = klo + (size_t)BATCH * NT * KFRAG;            // 16 MB

    prep_kernel<<<dim3(NT, BATCH), dim3(256), 0, stream>>>(k, v, khi, klo, vf);
    attn_kernel<<<dim3(BATCH, N / BM, 2), dim3(256), 0, stream>>>(q, o, khi, klo, vf);
}

// Round 5
// 162.878 us; speedup vs baseline: 1.0547x; 1.0547x over previous
//
#include <hip/hip_runtime.h>

// pixelSNAIL causal attention, MI355X gfx950.
// B=32, N=1024, C=128, CM=256, fp32 in/out.
// softmax over FULL row, strict causal mask, then @V.
// R4: prep_kernel: coalesced global IO + LDS transpose (XOR-swizzled slots).
// R5: swapped QK^T (mfma(K,Q)) -> P lane-local; in-register P->A-frag via
//     cvt_pk_bf16 + permlane32/16_swap; dbuf prefetch, counted vmcnt.
// R6 (reverted): 32 rows/wave @ 1 block/CU -> stalls exposed.
// R7 (reverted): CM-split occupancy: TLP up but 1.8x work -> net loss.
// R8: K streamed through REGISTERS (16 coalesced dwordx4/wave/tile from the
//     prepacked frag buffer, single-buffered, compiler-counted vmcnt).
//     K-LDS staging + K LDS reads gone -> LDS-read demand ~1/3; barriers
//     exist only for V: one barrier per pvt iter, the denominator-only
//     region (~47% of tiles) is barrier-free. LDS 32 KB (V dbuf only).
//     qt remapped (y<8 ? y : 23-y) so each CU's round-robin block pair is
//     (q, 15-q) -> PV work identical (36 pvt-tiles) on every CU.

typedef __attribute__((ext_vector_type(8))) short short8;
typedef __attribute__((ext_vector_type(4))) float floatx4;

#define MFMA16(a, b, c) __builtin_amdgcn_mfma_f32_16x16x32_bf16((a), (b), (c), 0, 0, 0)

constexpr int N = 1024, C = 128, CM = 256, BATCH = 32;
constexpr int BM = 64;             // q rows per block (4 waves x 16 rows)
constexpr int BN = 32;             // keys per tile
constexpr int NT = N / BN;         // 32 tiles
constexpr int KFRAG = BN * C;      // 4096 bf16 per K tile (hi or lo)
constexpr int VFRAG = BN * CM;     // 8192 bf16 per V tile

__device__ __forceinline__ unsigned short f2bf(float x) {
    unsigned int u = __float_as_uint(x);
    u += 0x7fffu + ((u >> 16) & 1u);   // RNE
    return (unsigned short)(u >> 16);
}
__device__ __forceinline__ float bf2f(unsigned short h) {
    return __uint_as_float(((unsigned int)h) << 16);
}
__device__ __forceinline__ uint2 pack4(const unsigned short* s) {
    uint2 u;
    u.x = (unsigned)s[0] | ((unsigned)s[1] << 16);
    u.y = (unsigned)s[2] | ((unsigned)s[3] << 16);
    return u;
}
__device__ __forceinline__ void gl2lds16(const unsigned short* g, unsigned short* l) {
    __builtin_amdgcn_global_load_lds(
        (const __attribute__((address_space(1))) void*)g,
        (__attribute__((address_space(3))) void*)l, 16, 0, 0);
}

// ---------------- prepass: coalesced global IO, LDS transpose ----------------
// Output layouts (consumed by attn_kernel):
//  khi/klo chunk ch in [0,512):  rr=ch&15, qq=(ch>>4)&3, ks=(ch>>6)&3, t=ch>>8
//    khb[ch*8+j] = bf16hi(K[n0 + t*16 + rr][ks*32 + qq*8 + j])
//  vf chunk ch in [0,1024):      rr=ch&15, qq=(ch>>4)&3, ct=ch>>6
//    vfb[ch*8+j] = bf16(V[n0 + qq*8 + j][ct*16 + rr])
__global__ __launch_bounds__(256, 4)
void prep_kernel(const float* __restrict__ kg, const float* __restrict__ vg,
                 unsigned short* __restrict__ khi, unsigned short* __restrict__ klo,
                 unsigned short* __restrict__ vf)
{
    __shared__ __align__(16) unsigned short sKh[KFRAG];   // 8 KB
    __shared__ __align__(16) unsigned short sKl[KFRAG];   // 8 KB
    __shared__ __align__(16) unsigned short sV[VFRAG];    // 16 KB

    const int tid = threadIdx.x;
    const int l = tid & 63, w = tid >> 6;
    const int tile = blockIdx.x, bat = blockIdx.y;
    const int n0 = tile * BN;
    const float* kb = kg + ((size_t)bat * N + n0) * C;
    const float* vb = vg + ((size_t)bat * N + n0) * CM;

    // ---- K staging: contiguous float4 reads (1 KB/instr/wave) ----
#pragma unroll
    for (int it = 0; it < 4; ++it) {
        const int lin = tid + it * 256;
        const float4 x = *(const float4*)(kb + (size_t)lin * 4);
        const int cr = lin >> 1, h = lin & 1;
        const int slot = cr ^ ((cr >> 4) & 7);
        float xs[4] = {x.x, x.y, x.z, x.w};
        unsigned short hi[4], lo[4];
#pragma unroll
        for (int e = 0; e < 4; ++e) {
            unsigned short hb = f2bf(xs[e]);
            hi[e] = hb;
            lo[e] = f2bf(xs[e] - bf2f(hb));
        }
        *(uint2*)(&sKh[slot * 8 + h * 4]) = pack4(hi);
        *(uint2*)(&sKl[slot * 8 + h * 4]) = pack4(lo);
    }

    // ---- V staging: 4 contiguous row-segment float4 reads per group ----
#pragma unroll
    for (int g = 0; g < 2; ++g) {
        const int k0 = g * 16 + w * 4;
        float xa[4][4];   // [e][d] = V[k0+d][4l+e]
#pragma unroll
        for (int d = 0; d < 4; ++d) {
            const float4 t = *(const float4*)(vb + (size_t)(k0 + d) * CM + l * 4);
            xa[0][d] = t.x; xa[1][d] = t.y; xa[2][d] = t.z; xa[3][d] = t.w;
        }
        const int qq = k0 >> 3, j0 = k0 & 7;
#pragma unroll
        for (int e = 0; e < 4; ++e) {
            const int cm = l * 4 + e;
            const int ct = cm >> 4, rr = cm & 15;
            const int ch = ct * 64 + qq * 16 + rr;
            const int slot = ch ^ ((ch >> 6) & 15);
            unsigned short o[4];
#pragma unroll
            for (int d = 0; d < 4; ++d) o[d] = f2bf(xa[e][d]);
            *(uint2*)(&sV[slot * 8 + j0]) = pack4(o);
        }
    }

    __syncthreads();

    unsigned short* khb = khi + ((size_t)bat * NT + tile) * KFRAG;
    unsigned short* klb = klo + ((size_t)bat * NT + tile) * KFRAG;
    unsigned short* vfb = vf + ((size_t)bat * NT + tile) * VFRAG;

    // ---- K out: linear b128 LDS reads, coalesced 16 B/lane global stores ----
#pragma unroll
    for (int it = 0; it < 2; ++it) {
        const int oc = tid + it * 256;
        const int cr = ((oc & 15) + ((oc >> 8) << 4)) * 16 + ((oc >> 6) & 3) * 4 + ((oc >> 4) & 3);
        const int slot = cr ^ ((cr >> 4) & 7);
        *(uint4*)(khb + (size_t)oc * 8) = *(const uint4*)(&sKh[slot * 8]);
        *(uint4*)(klb + (size_t)oc * 8) = *(const uint4*)(&sKl[slot * 8]);
    }
    // ---- V out ----
#pragma unroll
    for (int it = 0; it < 4; ++it) {
        const int oc = tid + it * 256;
        const int slot = oc ^ ((oc >> 6) & 15);
        *(uint4*)(vfb + (size_t)oc * 8) = *(const uint4*)(&sV[slot * 8]);
    }
}

// ---------------- main attention kernel ----------------
__global__ __launch_bounds__(256, 2)
void attn_kernel(const float* __restrict__ qg, float* __restrict__ og,
                 const unsigned short* __restrict__ khi,
                 const unsigned short* __restrict__ klo,
                 const unsigned short* __restrict__ vf)
{
    __shared__ __align__(16) unsigned short sV[2][VFRAG];    // 32 KB dbuf (V only)

    const int tid = threadIdx.x;
    const int w = tid >> 6, ln = tid & 63;
    const int r = ln & 15, qd = ln >> 4;
    const int bat = blockIdx.x;   // batch on x: linear%8 = bat%8 -> same XCD per batch
    const int by = blockIdx.y;
    // CU i gets blocks y=i/32 and y=i/32+8 (round-robin). Map so the pair is
    // (q, 15-q): equal PV-tile count (36) on every CU.
    const int qt = (by < 8) ? by : 23 - by;
    const int q0 = qt * BM;

    const float* qb = qg + (size_t)bat * N * C;
    float* ob = og + (size_t)bat * N * CM;
    const unsigned short* khb = khi + (size_t)bat * NT * KFRAG;
    const unsigned short* klb = klo + (size_t)bat * NT * KFRAG;
    const unsigned short* vfb = vf + (size_t)bat * NT * VFRAG;

    // Q fragments for this wave's 16 rows (q0 + w*16 + r), hi/lo split
    short8 qhi[4], qlo[4];
    {
        const float* qr = qb + (size_t)(q0 + w * 16 + r) * C + qd * 8;
#pragma unroll
        for (int ks = 0; ks < 4; ++ks) {
            float4 a = *(const float4*)(qr + ks * 32);
            float4 b = *(const float4*)(qr + ks * 32 + 4);
            float xs[8] = {a.x, a.y, a.z, a.w, b.x, b.y, b.z, b.w};
            short8 h, l;
#pragma unroll
            for (int j = 0; j < 8; ++j) {
                unsigned short hb = f2bf(xs[j]);
                h[j] = (short)hb;
                l[j] = (short)f2bf(xs[j] - bf2f(hb));
            }
            qhi[ks] = h;
            qlo[ks] = l;
        }
    }

    floatx4 oacc[16];
#pragma unroll
    for (int ct = 0; ct < 16; ++ct) oacc[ct] = (floatx4){0.f, 0.f, 0.f, 0.f};
    float lsum = 0.f;
    const int qrow = q0 + w * 16 + r;       // swapped-QK^T: lane owns ONE q-row

    // K fragment registers (single-buffered, 64 VGPRs): lane ln's chunks.
    short8 bh[2][4], bl[2][4];
    const unsigned short* khl = khb + (size_t)ln * 8;   // lane base, hi
    const unsigned short* kll = klb + (size_t)ln * 8;   // lane base, lo
#pragma unroll
    for (int t2 = 0; t2 < 2; ++t2)
#pragma unroll
        for (int ks = 0; ks < 4; ++ks) {
            bh[t2][ks] = *(const short8*)(khl + (t2 * 4 + ks) * 512);
            bl[t2][ks] = *(const short8*)(kll + (t2 * 4 + ks) * 512);
        }
    // V(0) into buffer 0
#pragma unroll
    for (int i = 0; i < 4; ++i)
        gl2lds16(vfb + (size_t)(tid + i * 256) * 8, &sV[0][(tid + i * 256) * 8]);
    asm volatile("s_waitcnt vmcnt(0)" ::: "memory");
    asm volatile("s_barrier" ::: "memory");

#pragma unroll 2
    for (int tile = 0; tile < NT; ++tile) {
        const int cb = tile & 1;
        const bool pvt  = (tile <= 2 * qt + 1);
        const bool pvtn = (tile + 1 <= 2 * qt + 1);   // implies tile+1 < NT

        // (A) issue V(t+1) first (max flight time; barrier at end of t-1
        //     already cleared this buffer's readers).
        if (pvtn) {
            const unsigned short* vs = vfb + (size_t)(tile + 1) * VFRAG;
            unsigned short* dv = &sV[cb ^ 1][0];
#pragma unroll
            for (int i = 0; i < 4; ++i)
                gl2lds16(vs + (size_t)(tid + i * 256) * 8, dv + (tid + i * 256) * 8);
        }
        // compiler fence: V issues stay BEFORE the K(t+1) register loads in
        // the VMEM queue (vmcnt(16) below drains the oldest 4 = V).
        asm volatile("" ::: "memory");

        // (B) swapped QK^T bf16x3 from K registers: D[key][qrow]
        float pk[8];
#pragma unroll
        for (int t = 0; t < 2; ++t) {
            floatx4 a0 = (floatx4){0.f, 0.f, 0.f, 0.f};
            floatx4 a1 = (floatx4){0.f, 0.f, 0.f, 0.f};
            floatx4 a2 = (floatx4){0.f, 0.f, 0.f, 0.f};
#pragma unroll
            for (int ks = 0; ks < 4; ++ks) {
                a0 = MFMA16(bh[t][ks], qhi[ks], a0);   // A=K -> rows=keys, cols=qrows
                a1 = MFMA16(bh[t][ks], qlo[ks], a1);
                a2 = MFMA16(bl[t][ks], qhi[ks], a2);
            }
            const int kbase = tile * BN + t * 16 + qd * 4;
#pragma unroll
            for (int rg = 0; rg < 4; ++rg) {
                float s = a0[rg] + a1[rg] + a2[rg];
                float p = __expf(s - 40.0f);
                lsum += p;                                  // full-row denominator
                pk[t * 4 + rg] = (kbase + rg < qrow) ? p : 0.0f;  // strict causal
            }
        }

        // (C) load K(t+1) into the (now free) K registers; latency hidden
        //     under exp/PV here + barrier wait + next QK^T's compiler wait.
        if (tile + 1 < NT) {
            const unsigned short* kh1 = khl + (size_t)(tile + 1) * KFRAG;
            const unsigned short* kl1 = kll + (size_t)(tile + 1) * KFRAG;
#pragma unroll
            for (int t2 = 0; t2 < 2; ++t2)
#pragma unroll
                for (int ks = 0; ks < 4; ++ks) {
                    bh[t2][ks] = *(const short8*)(kh1 + (t2 * 4 + ks) * 512);
                    bl[t2][ks] = *(const short8*)(kl1 + (t2 * 4 + ks) * 512);
                }
        }

        // (D) PV: P->A-frag in-register (cvt_pk + permlane), V from LDS
        if (pvt) {
            unsigned int w0, w1, w2, w3;
            asm("v_cvt_pk_bf16_f32 %0, %1, %2" : "=v"(w0) : "v"(pk[0]), "v"(pk[1]));
            asm("v_cvt_pk_bf16_f32 %0, %1, %2" : "=v"(w1) : "v"(pk[2]), "v"(pk[3]));
            asm("v_cvt_pk_bf16_f32 %0, %1, %2" : "=v"(w2) : "v"(pk[4]), "v"(pk[5]));
            asm("v_cvt_pk_bf16_f32 %0, %1, %2" : "=v"(w3) : "v"(pk[6]), "v"(pk[7]));
            asm("v_permlane32_swap_b32 %0, %1" : "+v"(w0), "+v"(w2));
            asm("v_permlane16_swap_b32 %0, %1" : "+v"(w0), "+v"(w2));
            asm("v_permlane32_swap_b32 %0, %1" : "+v"(w1), "+v"(w3));
            asm("v_permlane16_swap_b32 %0, %1" : "+v"(w1), "+v"(w3));
            uint4 apu = make_uint4(w0, w1, w2, w3);   // keys (0,1)(2,3)(4,5)(6,7)+8qd
            short8 ap = *(const short8*)&apu;
#pragma unroll
            for (int ct = 0; ct < 16; ++ct) {
                short8 bv = *(const short8*)(&sV[cb][(ct * 64 + ln) * 8]);
                oacc[ct] = MFMA16(ap, bv, oacc[ct]);
            }
        }

        // (E) sync only while V is live: drain V(t+1) (oldest 4 VMEM ops,
        //     K(t+1) stays in flight), then barrier. Non-pvt region: nothing.
        if (pvtn) {
            asm volatile("s_waitcnt vmcnt(16)" ::: "memory");
            asm volatile("s_barrier" ::: "memory");
        }
    }

    // ---- denominator: reduce across the 4 qd groups (lane owns row r) ----
    float vtot = lsum;
    vtot += __shfl_xor(vtot, 16);
    vtot += __shfl_xor(vtot, 32);

    // ---- divide + store ----
#pragma unroll
    for (int rg = 0; rg < 4; ++rg) {
        float inv = 1.0f / __shfl(vtot, qd * 4 + rg);   // lane qd*4+rg has row qd*4+rg
        float* orow = ob + (size_t)(q0 + w * 16 + qd * 4 + rg) * CM;
#pragma unroll
        for (int ct = 0; ct < 16; ++ct)
            orow[ct * 16 + r] = oacc[ct][rg] * inv;
    }
}

extern "C" void kernel_launch(void* const* d_in, const int* in_sizes, int n_in,
                              void* d_out, int out_size, void* d_ws, size_t ws_size,
                              hipStream_t stream) {
    const float* q = (const float*)d_in[0];
    const float* k = (const float*)d_in[1];
    const float* v = (const float*)d_in[2];
    float* o = (float*)d_out;
    (void)n_in; (void)in_sizes; (void)out_size; (void)ws_size;

    unsigned short* khi = (unsigned short*)d_ws;                       // 8 MB
    unsigned short* klo = khi + (size_t)BATCH * NT * KFRAG;            // 8 MB
    unsigned short* vf  = klo + (size_t)BATCH * NT * KFRAG;            // 16 MB

    prep_kernel<<<dim3(NT, BATCH), dim3(256), 0, stream>>>(k, v, khi, klo, vf);
    attn_kernel<<<dim3(BATCH, N / BM), dim3(256), 0, stream>>>(q, o, khi, klo, vf);
}

// Round 6
// 153.685 us; speedup vs baseline: 1.1178x; 1.0598x over previous
//
#include <hip/hip_runtime.h>

// pixelSNAIL causal attention, MI355X gfx950.
// B=32, N=1024, C=128, CM=256, fp32 in/out.
// softmax over FULL row, strict causal mask, then @V.
// R4: prep_kernel: coalesced global IO + LDS transpose (XOR-swizzled slots).
// R5: swapped QK^T (mfma(K,Q)) -> P lane-local; in-register P->A-frag via
//     cvt_pk_bf16 + permlane32/16_swap; K and V double-buffered, prefetched
//     one tile ahead, counted vmcnt(8/4/0).  [59 us verified]
// R6 (reverted): 32 rows/wave @ 1 block/CU -> stalls exposed.
// R7 (reverted): CM-split occupancy: TLP up but 1.8x work -> net loss.
// R8 (reverted): K in registers -> 4x L2 traffic (LDS broadcast lost).
// R9: R5 +
//  - CU load balance: blocks (bat,by),(bat,by+8) share a CU; qt remap
//    (by<8 ? by : 23-by) pairs (q,15-q) -> every CU gets exactly 36 pvt
//    tiles (was 20..48, 2.4x makespan imbalance).
//  - s_setprio(1) around QK^T/PV MFMA clusters: the CU's two blocks run on
//    independent barriers -> wave phase diversity -> T5 regime (+4-7% attn).

typedef __attribute__((ext_vector_type(8))) short short8;
typedef __attribute__((ext_vector_type(4))) float floatx4;

#define MFMA16(a, b, c) __builtin_amdgcn_mfma_f32_16x16x32_bf16((a), (b), (c), 0, 0, 0)

constexpr int N = 1024, C = 128, CM = 256, BATCH = 32;
constexpr int BM = 64;             // q rows per block (4 waves x 16 rows)
constexpr int BN = 32;             // keys per tile
constexpr int NT = N / BN;         // 32 tiles
constexpr int KFRAG = BN * C;      // 4096 bf16 per K tile (hi or lo)
constexpr int VFRAG = BN * CM;     // 8192 bf16 per V tile

__device__ __forceinline__ unsigned short f2bf(float x) {
    unsigned int u = __float_as_uint(x);
    u += 0x7fffu + ((u >> 16) & 1u);   // RNE
    return (unsigned short)(u >> 16);
}
__device__ __forceinline__ float bf2f(unsigned short h) {
    return __uint_as_float(((unsigned int)h) << 16);
}
__device__ __forceinline__ uint2 pack4(const unsigned short* s) {
    uint2 u;
    u.x = (unsigned)s[0] | ((unsigned)s[1] << 16);
    u.y = (unsigned)s[2] | ((unsigned)s[3] << 16);
    return u;
}
__device__ __forceinline__ void gl2lds16(const unsigned short* g, unsigned short* l) {
    __builtin_amdgcn_global_load_lds(
        (const __attribute__((address_space(1))) void*)g,
        (__attribute__((address_space(3))) void*)l, 16, 0, 0);
}

// ---------------- prepass: coalesced global IO, LDS transpose ----------------
// Output layouts (consumed by attn_kernel):
//  khi/klo chunk ch in [0,512):  rr=ch&15, qq=(ch>>4)&3, ks=(ch>>6)&3, t=ch>>8
//    khb[ch*8+j] = bf16hi(K[n0 + t*16 + rr][ks*32 + qq*8 + j])
//  vf chunk ch in [0,1024):      rr=ch&15, qq=(ch>>4)&3, ct=ch>>6
//    vfb[ch*8+j] = bf16(V[n0 + qq*8 + j][ct*16 + rr])
__global__ __launch_bounds__(256, 4)
void prep_kernel(const float* __restrict__ kg, const float* __restrict__ vg,
                 unsigned short* __restrict__ khi, unsigned short* __restrict__ klo,
                 unsigned short* __restrict__ vf)
{
    __shared__ __align__(16) unsigned short sKh[KFRAG];   // 8 KB
    __shared__ __align__(16) unsigned short sKl[KFRAG];   // 8 KB
    __shared__ __align__(16) unsigned short sV[VFRAG];    // 16 KB

    const int tid = threadIdx.x;
    const int l = tid & 63, w = tid >> 6;
    const int tile = blockIdx.x, bat = blockIdx.y;
    const int n0 = tile * BN;
    const float* kb = kg + ((size_t)bat * N + n0) * C;
    const float* vb = vg + ((size_t)bat * N + n0) * CM;

    // ---- K staging: contiguous float4 reads (1 KB/instr/wave) ----
#pragma unroll
    for (int it = 0; it < 4; ++it) {
        const int lin = tid + it * 256;
        const float4 x = *(const float4*)(kb + (size_t)lin * 4);
        const int cr = lin >> 1, h = lin & 1;
        const int slot = cr ^ ((cr >> 4) & 7);
        float xs[4] = {x.x, x.y, x.z, x.w};
        unsigned short hi[4], lo[4];
#pragma unroll
        for (int e = 0; e < 4; ++e) {
            unsigned short hb = f2bf(xs[e]);
            hi[e] = hb;
            lo[e] = f2bf(xs[e] - bf2f(hb));
        }
        *(uint2*)(&sKh[slot * 8 + h * 4]) = pack4(hi);
        *(uint2*)(&sKl[slot * 8 + h * 4]) = pack4(lo);
    }

    // ---- V staging: 4 contiguous row-segment float4 reads per group ----
#pragma unroll
    for (int g = 0; g < 2; ++g) {
        const int k0 = g * 16 + w * 4;
        float xa[4][4];   // [e][d] = V[k0+d][4l+e]
#pragma unroll
        for (int d = 0; d < 4; ++d) {
            const float4 t = *(const float4*)(vb + (size_t)(k0 + d) * CM + l * 4);
            xa[0][d] = t.x; xa[1][d] = t.y; xa[2][d] = t.z; xa[3][d] = t.w;
        }
        const int qq = k0 >> 3, j0 = k0 & 7;
#pragma unroll
        for (int e = 0; e < 4; ++e) {
            const int cm = l * 4 + e;
            const int ct = cm >> 4, rr = cm & 15;
            const int ch = ct * 64 + qq * 16 + rr;
            const int slot = ch ^ ((ch >> 6) & 15);
            unsigned short o[4];
#pragma unroll
            for (int d = 0; d < 4; ++d) o[d] = f2bf(xa[e][d]);
            *(uint2*)(&sV[slot * 8 + j0]) = pack4(o);
        }
    }

    __syncthreads();

    unsigned short* khb = khi + ((size_t)bat * NT + tile) * KFRAG;
    unsigned short* klb = klo + ((size_t)bat * NT + tile) * KFRAG;
    unsigned short* vfb = vf + ((size_t)bat * NT + tile) * VFRAG;

    // ---- K out: linear b128 LDS reads, coalesced 16 B/lane global stores ----
#pragma unroll
    for (int it = 0; it < 2; ++it) {
        const int oc = tid + it * 256;
        const int cr = ((oc & 15) + ((oc >> 8) << 4)) * 16 + ((oc >> 6) & 3) * 4 + ((oc >> 4) & 3);
        const int slot = cr ^ ((cr >> 4) & 7);
        *(uint4*)(khb + (size_t)oc * 8) = *(const uint4*)(&sKh[slot * 8]);
        *(uint4*)(klb + (size_t)oc * 8) = *(const uint4*)(&sKl[slot * 8]);
    }
    // ---- V out ----
#pragma unroll
    for (int it = 0; it < 4; ++it) {
        const int oc = tid + it * 256;
        const int slot = oc ^ ((oc >> 6) & 15);
        *(uint4*)(vfb + (size_t)oc * 8) = *(const uint4*)(&sV[slot * 8]);
    }
}

// ---------------- main attention kernel ----------------
__global__ __launch_bounds__(256, 2)
void attn_kernel(const float* __restrict__ qg, float* __restrict__ og,
                 const unsigned short* __restrict__ khi,
                 const unsigned short* __restrict__ klo,
                 const unsigned short* __restrict__ vf)
{
    __shared__ __align__(16) unsigned short sKhi[2][KFRAG];  // 16 KB dbuf
    __shared__ __align__(16) unsigned short sKlo[2][KFRAG];  // 16 KB dbuf
    __shared__ __align__(16) unsigned short sV[2][VFRAG];    // 32 KB dbuf

    const int tid = threadIdx.x;
    const int w = tid >> 6, ln = tid & 63;
    const int r = ln & 15, qd = ln >> 4;
    const int bat = blockIdx.x;   // batch on x: linear%8 = bat%8 -> same XCD per batch
    const int by = blockIdx.y;
    // CU i hosts blocks (bat, by) and (bat, by+8) (linear distance 256 =
    // one dispatch round-robin). Remap so the resident pair is (q, 15-q):
    // pvt-tile total = 36 on every CU (direct mapping gave 20..48).
    const int qt = (by < 8) ? by : 23 - by;
    const int q0 = qt * BM;

    const float* qb = qg + (size_t)bat * N * C;
    float* ob = og + (size_t)bat * N * CM;
    const unsigned short* khb = khi + (size_t)bat * NT * KFRAG;
    const unsigned short* klb = klo + (size_t)bat * NT * KFRAG;
    const unsigned short* vfb = vf + (size_t)bat * NT * VFRAG;

    // Q fragments for this wave's 16 rows (q0 + w*16 + r), hi/lo split
    short8 qhi[4], qlo[4];
    {
        const float* qr = qb + (size_t)(q0 + w * 16 + r) * C + qd * 8;
#pragma unroll
        for (int ks = 0; ks < 4; ++ks) {
            float4 a = *(const float4*)(qr + ks * 32);
            float4 b = *(const float4*)(qr + ks * 32 + 4);
            float xs[8] = {a.x, a.y, a.z, a.w, b.x, b.y, b.z, b.w};
            short8 h, l;
#pragma unroll
            for (int j = 0; j < 8; ++j) {
                unsigned short hb = f2bf(xs[j]);
                h[j] = (short)hb;
                l[j] = (short)f2bf(xs[j] - bf2f(hb));
            }
            qhi[ks] = h;
            qlo[ks] = l;
        }
    }

    floatx4 oacc[16];
#pragma unroll
    for (int ct = 0; ct < 16; ++ct) oacc[ct] = (floatx4){0.f, 0.f, 0.f, 0.f};
    float lsum = 0.f;                       // this lane's q-row partial denom
    const int qrow = q0 + w * 16 + r;       // swapped-QK^T: lane owns ONE q-row

    // prologue: prefetch K(0) + V(0) into buffer 0 (8 loads/thread)
    gl2lds16(khb + (size_t)tid * 8,         &sKhi[0][tid * 8]);
    gl2lds16(khb + (size_t)(tid + 256) * 8, &sKhi[0][(tid + 256) * 8]);
    gl2lds16(klb + (size_t)tid * 8,         &sKlo[0][tid * 8]);
    gl2lds16(klb + (size_t)(tid + 256) * 8, &sKlo[0][(tid + 256) * 8]);
#pragma unroll
    for (int i = 0; i < 4; ++i)
        gl2lds16(vfb + (size_t)(tid + i * 256) * 8, &sV[0][(tid + i * 256) * 8]);

    for (int tile = 0; tile < NT; ++tile) {
        const bool pvt = (tile <= 2 * qt + 1);   // tile holds keys < some row in block
        const int cb = tile & 1;

        // prefetch K(t+1) (+ V(t+1) if needed) into the other buffers; the
        // counted vmcnt leaves exactly the just-issued loads in flight.
        if (tile + 1 < NT) {
            const unsigned short* k1 = khb + (size_t)(tile + 1) * KFRAG;
            const unsigned short* l1 = klb + (size_t)(tile + 1) * KFRAG;
            unsigned short* dh = &sKhi[cb ^ 1][0];
            unsigned short* dl = &sKlo[cb ^ 1][0];
            gl2lds16(k1 + (size_t)tid * 8,         dh + tid * 8);
            gl2lds16(k1 + (size_t)(tid + 256) * 8, dh + (tid + 256) * 8);
            gl2lds16(l1 + (size_t)tid * 8,         dl + tid * 8);
            gl2lds16(l1 + (size_t)(tid + 256) * 8, dl + (tid + 256) * 8);
            if (tile + 1 <= 2 * qt + 1) {        // V(t+1) needed
                const unsigned short* vs = vfb + (size_t)(tile + 1) * VFRAG;
                unsigned short* dv = &sV[cb ^ 1][0];
#pragma unroll
                for (int i = 0; i < 4; ++i)
                    gl2lds16(vs + (size_t)(tid + i * 256) * 8, dv + (tid + i * 256) * 8);
                asm volatile("s_waitcnt vmcnt(8)" ::: "memory");   // drain K(t)+V(t)
            } else {
                asm volatile("s_waitcnt vmcnt(4)" ::: "memory");   // drain K(t)(+V(t))
            }
        } else {
            asm volatile("s_waitcnt vmcnt(0)" ::: "memory");
        }
        asm volatile("s_barrier" ::: "memory");   // all waves' K(t)/V(t) staged

        // ---- swapped QK^T bf16x3: D[key][qrow], 3 independent chains ----
        float pk[8];
#pragma unroll
        for (int t = 0; t < 2; ++t) {
            floatx4 a0 = (floatx4){0.f, 0.f, 0.f, 0.f};
            floatx4 a1 = (floatx4){0.f, 0.f, 0.f, 0.f};
            floatx4 a2 = (floatx4){0.f, 0.f, 0.f, 0.f};
            __builtin_amdgcn_s_setprio(1);        // favor this wave's MFMA burst
#pragma unroll
            for (int ks = 0; ks < 4; ++ks) {
                short8 bh = *(const short8*)(&sKhi[cb][(((t * 4 + ks) * 64) + ln) * 8]);
                short8 bl = *(const short8*)(&sKlo[cb][(((t * 4 + ks) * 64) + ln) * 8]);
                a0 = MFMA16(bh, qhi[ks], a0);     // A=K -> rows=keys, cols=qrows
                a1 = MFMA16(bh, qlo[ks], a1);
                a2 = MFMA16(bl, qhi[ks], a2);
            }
            __builtin_amdgcn_s_setprio(0);
            const int kbase = tile * BN + t * 16 + qd * 4;
#pragma unroll
            for (int rg = 0; rg < 4; ++rg) {
                float s = a0[rg] + a1[rg] + a2[rg];
                float p = __expf(s - 40.0f);
                lsum += p;                                  // full-row denominator
                pk[t * 4 + rg] = (kbase + rg < qrow) ? p : 0.0f;  // strict causal
            }
        }

        // ---- PV: P->A-frag built in-register (cvt_pk + permlane swaps) ----
        if (pvt) {
            // w0..w3 = packed bf16 pairs: (t0 k0,k1)(t0 k2,k3)(t1 k0,k1)(t1 k2,k3)
            unsigned int w0, w1, w2, w3;
            asm("v_cvt_pk_bf16_f32 %0, %1, %2" : "=v"(w0) : "v"(pk[0]), "v"(pk[1]));
            asm("v_cvt_pk_bf16_f32 %0, %1, %2" : "=v"(w1) : "v"(pk[2]), "v"(pk[3]));
            asm("v_cvt_pk_bf16_f32 %0, %1, %2" : "=v"(w2) : "v"(pk[4]), "v"(pk[5]));
            asm("v_cvt_pk_bf16_f32 %0, %1, %2" : "=v"(w3) : "v"(pk[6]), "v"(pk[7]));
            // lane group qd needs keys 8qd..8qd+7 of its row r:
            // (o0,o2) = permlane16_swap(permlane32_swap(w0, w2)); same for (w1,w3).
            asm("v_permlane32_swap_b32 %0, %1" : "+v"(w0), "+v"(w2));
            asm("v_permlane16_swap_b32 %0, %1" : "+v"(w0), "+v"(w2));
            asm("v_permlane32_swap_b32 %0, %1" : "+v"(w1), "+v"(w3));
            asm("v_permlane16_swap_b32 %0, %1" : "+v"(w1), "+v"(w3));
            uint4 apu = make_uint4(w0, w1, w2, w3);   // keys (0,1)(2,3)(4,5)(6,7)+8qd
            short8 ap = *(const short8*)&apu;
            __builtin_amdgcn_s_setprio(1);
#pragma unroll
            for (int ct = 0; ct < 16; ++ct) {
                short8 bv = *(const short8*)(&sV[cb][(ct * 64 + ln) * 8]);
                oacc[ct] = MFMA16(ap, bv, oacc[ct]);
            }
            __builtin_amdgcn_s_setprio(0);
        }
        asm volatile("s_barrier" ::: "memory");   // readers done before next overwrite
    }

    // ---- denominator: reduce across the 4 qd groups (lane owns row r) ----
    float vtot = lsum;
    vtot += __shfl_xor(vtot, 16);
    vtot += __shfl_xor(vtot, 32);
    // vtot = full denom for row (q0 + w*16 + r) on every lane

    // ---- divide + store ----
#pragma unroll
    for (int rg = 0; rg < 4; ++rg) {
        float inv = 1.0f / __shfl(vtot, qd * 4 + rg);   // lane qd*4+rg has row qd*4+rg
        float* orow = ob + (size_t)(q0 + w * 16 + qd * 4 + rg) * CM;
#pragma unroll
        for (int ct = 0; ct < 16; ++ct)
            orow[ct * 16 + r] = oacc[ct][rg] * inv;
    }
}

extern "C" void kernel_launch(void* const* d_in, const int* in_sizes, int n_in,
                              void* d_out, int out_size, void* d_ws, size_t ws_size,
                              hipStream_t stream) {
    const float* q = (const float*)d_in[0];
    const float* k = (const float*)d_in[1];
    const float* v = (const float*)d_in[2];
    float* o = (float*)d_out;
    (void)n_in; (void)in_sizes; (void)out_size; (void)ws_size;

    unsigned short* khi = (unsigned short*)d_ws;                       // 8 MB
    unsigned short* klo = khi + (size_t)BATCH * NT * KFRAG;            // 8 MB
    unsigned short* vf  = klo + (size_t)BATCH * NT * KFRAG;            // 16 MB

    prep_kernel<<<dim3(NT, BATCH), dim3(256), 0, stream>>>(k, v, khi, klo, vf);
    attn_kernel<<<dim3(BATCH, N / BM), dim3(256), 0, stream>>>(q, o, khi, klo, vf);
}

// Round 8
// 149.959 us; speedup vs baseline: 1.1456x; 1.0249x over previous
//
#include <hip/hip_runtime.h>

// pixelSNAIL causal attention, MI355X gfx950.
// B=32, N=1024, C=128, CM=256, fp32 in/out.
// softmax over FULL row, strict causal mask, then @V.
// R4: prep_kernel: coalesced global IO + LDS transpose (XOR-swizzled slots).
// R5: swapped QK^T (mfma(K,Q)) -> P lane-local; in-register P->A-frag via
//     cvt_pk_bf16 + permlane32/16_swap; K and V double-buffered.  [58.8 us]
// R6 (reverted): 32 rows/wave @ 1 block/CU -> stalls exposed.
// R7 (reverted): CM-split occupancy: TLP up but 1.8x work -> net loss.
// R8 (reverted): K in registers -> 4x L2 traffic (LDS broadcast lost).
// R9 (reverted): qt-remap + setprio -> +2.9 us.
// R10 (reverted): key-split 8-wave + 16x16x16 PV -> NaN (16x16x16 frag
//      layout on gfx950 is HW-unverified; two novelties stacked = undebuggable).
// R11: R5 with ONE barrier per tile. Loads for t+1 are issued AFTER the
//      top-of-tile barrier: every wave past barrier(t) has finished its
//      t-1 compute, so nobody still reads the buffer being overwritten ->
//      the end-of-tile WAR barrier is provably unnecessary. vmcnt(0) drain
//      at top (nothing else in flight -> counted drain no longer needed).
//      All fragment math / staging / softmax / PV byte-identical to R5.

typedef __attribute__((ext_vector_type(8))) short short8;
typedef __attribute__((ext_vector_type(4))) float floatx4;

#define MFMA16(a, b, c) __builtin_amdgcn_mfma_f32_16x16x32_bf16((a), (b), (c), 0, 0, 0)

constexpr int N = 1024, C = 128, CM = 256, BATCH = 32;
constexpr int BM = 64;             // q rows per block (4 waves x 16 rows)
constexpr int BN = 32;             // keys per tile
constexpr int NT = N / BN;         // 32 tiles
constexpr int KFRAG = BN * C;      // 4096 bf16 per K tile (hi or lo)
constexpr int VFRAG = BN * CM;     // 8192 bf16 per V tile

__device__ __forceinline__ unsigned short f2bf(float x) {
    unsigned int u = __float_as_uint(x);
    u += 0x7fffu + ((u >> 16) & 1u);   // RNE
    return (unsigned short)(u >> 16);
}
__device__ __forceinline__ float bf2f(unsigned short h) {
    return __uint_as_float(((unsigned int)h) << 16);
}
__device__ __forceinline__ uint2 pack4(const unsigned short* s) {
    uint2 u;
    u.x = (unsigned)s[0] | ((unsigned)s[1] << 16);
    u.y = (unsigned)s[2] | ((unsigned)s[3] << 16);
    return u;
}
__device__ __forceinline__ void gl2lds16(const unsigned short* g, unsigned short* l) {
    __builtin_amdgcn_global_load_lds(
        (const __attribute__((address_space(1))) void*)g,
        (__attribute__((address_space(3))) void*)l, 16, 0, 0);
}

// ---------------- prepass: coalesced global IO, LDS transpose ----------------
// Output layouts (consumed by attn_kernel):
//  khi/klo chunk ch in [0,512):  rr=ch&15, qq=(ch>>4)&3, ks=(ch>>6)&3, t=ch>>8
//    khb[ch*8+j] = bf16hi(K[n0 + t*16 + rr][ks*32 + qq*8 + j])
//  vf chunk ch in [0,1024):      rr=ch&15, qq=(ch>>4)&3, ct=ch>>6
//    vfb[ch*8+j] = bf16(V[n0 + qq*8 + j][ct*16 + rr])
__global__ __launch_bounds__(256, 4)
void prep_kernel(const float* __restrict__ kg, const float* __restrict__ vg,
                 unsigned short* __restrict__ khi, unsigned short* __restrict__ klo,
                 unsigned short* __restrict__ vf)
{
    __shared__ __align__(16) unsigned short sKh[KFRAG];   // 8 KB
    __shared__ __align__(16) unsigned short sKl[KFRAG];   // 8 KB
    __shared__ __align__(16) unsigned short sV[VFRAG];    // 16 KB

    const int tid = threadIdx.x;
    const int l = tid & 63, w = tid >> 6;
    const int tile = blockIdx.x, bat = blockIdx.y;
    const int n0 = tile * BN;
    const float* kb = kg + ((size_t)bat * N + n0) * C;
    const float* vb = vg + ((size_t)bat * N + n0) * CM;

    // ---- K staging: contiguous float4 reads (1 KB/instr/wave) ----
#pragma unroll
    for (int it = 0; it < 4; ++it) {
        const int lin = tid + it * 256;
        const float4 x = *(const float4*)(kb + (size_t)lin * 4);
        const int cr = lin >> 1, h = lin & 1;
        const int slot = cr ^ ((cr >> 4) & 7);
        float xs[4] = {x.x, x.y, x.z, x.w};
        unsigned short hi[4], lo[4];
#pragma unroll
        for (int e = 0; e < 4; ++e) {
            unsigned short hb = f2bf(xs[e]);
            hi[e] = hb;
            lo[e] = f2bf(xs[e] - bf2f(hb));
        }
        *(uint2*)(&sKh[slot * 8 + h * 4]) = pack4(hi);
        *(uint2*)(&sKl[slot * 8 + h * 4]) = pack4(lo);
    }

    // ---- V staging: 4 contiguous row-segment float4 reads per group ----
#pragma unroll
    for (int g = 0; g < 2; ++g) {
        const int k0 = g * 16 + w * 4;
        float xa[4][4];   // [e][d] = V[k0+d][4l+e]
#pragma unroll
        for (int d = 0; d < 4; ++d) {
            const float4 t = *(const float4*)(vb + (size_t)(k0 + d) * CM + l * 4);
            xa[0][d] = t.x; xa[1][d] = t.y; xa[2][d] = t.z; xa[3][d] = t.w;
        }
        const int qq = k0 >> 3, j0 = k0 & 7;
#pragma unroll
        for (int e = 0; e < 4; ++e) {
            const int cm = l * 4 + e;
            const int ct = cm >> 4, rr = cm & 15;
            const int ch = ct * 64 + qq * 16 + rr;
            const int slot = ch ^ ((ch >> 6) & 15);
            unsigned short o[4];
#pragma unroll
            for (int d = 0; d < 4; ++d) o[d] = f2bf(xa[e][d]);
            *(uint2*)(&sV[slot * 8 + j0]) = pack4(o);
        }
    }

    __syncthreads();

    unsigned short* khb = khi + ((size_t)bat * NT + tile) * KFRAG;
    unsigned short* klb = klo + ((size_t)bat * NT + tile) * KFRAG;
    unsigned short* vfb = vf + ((size_t)bat * NT + tile) * VFRAG;

    // ---- K out: linear b128 LDS reads, coalesced 16 B/lane global stores ----
#pragma unroll
    for (int it = 0; it < 2; ++it) {
        const int oc = tid + it * 256;
        const int cr = ((oc & 15) + ((oc >> 8) << 4)) * 16 + ((oc >> 6) & 3) * 4 + ((oc >> 4) & 3);
        const int slot = cr ^ ((cr >> 4) & 7);
        *(uint4*)(khb + (size_t)oc * 8) = *(const uint4*)(&sKh[slot * 8]);
        *(uint4*)(klb + (size_t)oc * 8) = *(const uint4*)(&sKl[slot * 8]);
    }
    // ---- V out ----
#pragma unroll
    for (int it = 0; it < 4; ++it) {
        const int oc = tid + it * 256;
        const int slot = oc ^ ((oc >> 6) & 15);
        *(uint4*)(vfb + (size_t)oc * 8) = *(const uint4*)(&sV[slot * 8]);
    }
}

// ---------------- main attention kernel ----------------
__global__ __launch_bounds__(256, 2)
void attn_kernel(const float* __restrict__ qg, float* __restrict__ og,
                 const unsigned short* __restrict__ khi,
                 const unsigned short* __restrict__ klo,
                 const unsigned short* __restrict__ vf)
{
    __shared__ __align__(16) unsigned short sKhi[2][KFRAG];  // 16 KB dbuf
    __shared__ __align__(16) unsigned short sKlo[2][KFRAG];  // 16 KB dbuf
    __shared__ __align__(16) unsigned short sV[2][VFRAG];    // 32 KB dbuf

    const int tid = threadIdx.x;
    const int w = tid >> 6, ln = tid & 63;
    const int r = ln & 15, qd = ln >> 4;
    const int bat = blockIdx.x;   // batch on x: linear%8 = bat%8 -> same XCD per batch
    const int qt = blockIdx.y;
    const int q0 = qt * BM;

    const float* qb = qg + (size_t)bat * N * C;
    float* ob = og + (size_t)bat * N * CM;
    const unsigned short* khb = khi + (size_t)bat * NT * KFRAG;
    const unsigned short* klb = klo + (size_t)bat * NT * KFRAG;
    const unsigned short* vfb = vf + (size_t)bat * NT * VFRAG;

    // Q fragments for this wave's 16 rows (q0 + w*16 + r), hi/lo split
    short8 qhi[4], qlo[4];
    {
        const float* qr = qb + (size_t)(q0 + w * 16 + r) * C + qd * 8;
#pragma unroll
        for (int ks = 0; ks < 4; ++ks) {
            float4 a = *(const float4*)(qr + ks * 32);
            float4 b = *(const float4*)(qr + ks * 32 + 4);
            float xs[8] = {a.x, a.y, a.z, a.w, b.x, b.y, b.z, b.w};
            short8 h, l;
#pragma unroll
            for (int j = 0; j < 8; ++j) {
                unsigned short hb = f2bf(xs[j]);
                h[j] = (short)hb;
                l[j] = (short)f2bf(xs[j] - bf2f(hb));
            }
            qhi[ks] = h;
            qlo[ks] = l;
        }
    }

    floatx4 oacc[16];
#pragma unroll
    for (int ct = 0; ct < 16; ++ct) oacc[ct] = (floatx4){0.f, 0.f, 0.f, 0.f};
    float lsum = 0.f;                       // this lane's q-row partial denom
    const int qrow = q0 + w * 16 + r;       // swapped-QK^T: lane owns ONE q-row

    // prologue: prefetch K(0) + V(0) into buffer 0 (8 loads/thread)
    gl2lds16(khb + (size_t)tid * 8,         &sKhi[0][tid * 8]);
    gl2lds16(khb + (size_t)(tid + 256) * 8, &sKhi[0][(tid + 256) * 8]);
    gl2lds16(klb + (size_t)tid * 8,         &sKlo[0][tid * 8]);
    gl2lds16(klb + (size_t)(tid + 256) * 8, &sKlo[0][(tid + 256) * 8]);
#pragma unroll
    for (int i = 0; i < 4; ++i)
        gl2lds16(vfb + (size_t)(tid + i * 256) * 8, &sV[0][(tid + i * 256) * 8]);

    for (int tile = 0; tile < NT; ++tile) {
        const bool pvt  = (tile <= 2 * qt + 1);       // tile contributes to PV
        const bool pvtn = (tile + 1 <= 2 * qt + 1);   // next tile contributes
        const int cb = tile & 1;

        // drain THIS tile's staging (issued last iter / prologue); publish.
        // Nothing else is in flight here, so a full drain costs nothing.
        asm volatile("s_waitcnt vmcnt(0)" ::: "memory");
        asm volatile("s_barrier" ::: "memory");

        // issue next tile's loads into cb^1 AFTER the barrier: every wave
        // being past barrier(t) implies it finished iter t-1's compute, so
        // no wave still reads cb^1 -> WAR-safe with no second barrier.
        if (tile + 1 < NT) {
            const unsigned short* k1 = khb + (size_t)(tile + 1) * KFRAG;
            const unsigned short* l1 = klb + (size_t)(tile + 1) * KFRAG;
            unsigned short* dh = &sKhi[cb ^ 1][0];
            unsigned short* dl = &sKlo[cb ^ 1][0];
            gl2lds16(k1 + (size_t)tid * 8,         dh + tid * 8);
            gl2lds16(k1 + (size_t)(tid + 256) * 8, dh + (tid + 256) * 8);
            gl2lds16(l1 + (size_t)tid * 8,         dl + tid * 8);
            gl2lds16(l1 + (size_t)(tid + 256) * 8, dl + (tid + 256) * 8);
            if (pvtn) {
                const unsigned short* vs = vfb + (size_t)(tile + 1) * VFRAG;
                unsigned short* dv = &sV[cb ^ 1][0];
#pragma unroll
                for (int i = 0; i < 4; ++i)
                    gl2lds16(vs + (size_t)(tid + i * 256) * 8, dv + (tid + i * 256) * 8);
            }
        }

        // ---- swapped QK^T bf16x3: D[key][qrow], 3 independent chains ----
        float pk[8];
#pragma unroll
        for (int t = 0; t < 2; ++t) {
            floatx4 a0 = (floatx4){0.f, 0.f, 0.f, 0.f};
            floatx4 a1 = (floatx4){0.f, 0.f, 0.f, 0.f};
            floatx4 a2 = (floatx4){0.f, 0.f, 0.f, 0.f};
#pragma unroll
            for (int ks = 0; ks < 4; ++ks) {
                short8 bh = *(const short8*)(&sKhi[cb][(((t * 4 + ks) * 64) + ln) * 8]);
                short8 bl = *(const short8*)(&sKlo[cb][(((t * 4 + ks) * 64) + ln) * 8]);
                a0 = MFMA16(bh, qhi[ks], a0);     // A=K -> rows=keys, cols=qrows
                a1 = MFMA16(bh, qlo[ks], a1);
                a2 = MFMA16(bl, qhi[ks], a2);
            }
            const int kbase = tile * BN + t * 16 + qd * 4;
#pragma unroll
            for (int rg = 0; rg < 4; ++rg) {
                float s = a0[rg] + a1[rg] + a2[rg];
                float p = __expf(s - 40.0f);
                lsum += p;                                  // full-row denominator
                pk[t * 4 + rg] = (kbase + rg < qrow) ? p : 0.0f;  // strict causal
            }
        }

        // ---- PV: P->A-frag built in-register (cvt_pk + permlane swaps) ----
        if (pvt) {
            // w0..w3 = packed bf16 pairs: (t0 k0,k1)(t0 k2,k3)(t1 k0,k1)(t1 k2,k3)
            unsigned int w0, w1, w2, w3;
            asm("v_cvt_pk_bf16_f32 %0, %1, %2" : "=v"(w0) : "v"(pk[0]), "v"(pk[1]));
            asm("v_cvt_pk_bf16_f32 %0, %1, %2" : "=v"(w1) : "v"(pk[2]), "v"(pk[3]));
            asm("v_cvt_pk_bf16_f32 %0, %1, %2" : "=v"(w2) : "v"(pk[4]), "v"(pk[5]));
            asm("v_cvt_pk_bf16_f32 %0, %1, %2" : "=v"(w3) : "v"(pk[6]), "v"(pk[7]));
            // lane group qd needs keys 8qd..8qd+7 of its row r:
            // (o0,o2) = permlane16_swap(permlane32_swap(w0, w2)); same for (w1,w3).
            asm("v_permlane32_swap_b32 %0, %1" : "+v"(w0), "+v"(w2));
            asm("v_permlane16_swap_b32 %0, %1" : "+v"(w0), "+v"(w2));
            asm("v_permlane32_swap_b32 %0, %1" : "+v"(w1), "+v"(w3));
            asm("v_permlane16_swap_b32 %0, %1" : "+v"(w1), "+v"(w3));
            uint4 apu = make_uint4(w0, w1, w2, w3);   // keys (0,1)(2,3)(4,5)(6,7)+8qd
            short8 ap = *(const short8*)&apu;
#pragma unroll
            for (int ct = 0; ct < 16; ++ct) {
                short8 bv = *(const short8*)(&sV[cb][(ct * 64 + ln) * 8]);
                oacc[ct] = MFMA16(ap, bv, oacc[ct]);
            }
        }
        // no end-of-tile barrier: WAR protection moved to issue-after-barrier.
    }

    // ---- denominator: reduce across the 4 qd groups (lane owns row r) ----
    float vtot = lsum;
    vtot += __shfl_xor(vtot, 16);
    vtot += __shfl_xor(vtot, 32);
    // vtot = full denom for row (q0 + w*16 + r) on every lane

    // ---- divide + store ----
#pragma unroll
    for (int rg = 0; rg < 4; ++rg) {
        float inv = 1.0f / __shfl(vtot, qd * 4 + rg);   // lane qd*4+rg has row qd*4+rg
        float* orow = ob + (size_t)(q0 + w * 16 + qd * 4 + rg) * CM;
#pragma unroll
        for (int ct = 0; ct < 16; ++ct)
            orow[ct * 16 + r] = oacc[ct][rg] * inv;
    }
}

extern "C" void kernel_launch(void* const* d_in, const int* in_sizes, int n_in,
                              void* d_out, int out_size, void* d_ws, size_t ws_size,
                              hipStream_t stream) {
    const float* q = (const float*)d_in[0];
    const float* k = (const float*)d_in[1];
    const float* v = (const float*)d_in[2];
    float* o = (float*)d_out;
    (void)n_in; (void)in_sizes; (void)out_size; (void)ws_size;

    unsigned short* khi = (unsigned short*)d_ws;                       // 8 MB
    unsigned short* klo = khi + (size_t)BATCH * NT * KFRAG;            // 8 MB
    unsigned short* vf  = klo + (size_t)BATCH * NT * KFRAG;            // 16 MB

    prep_kernel<<<dim3(NT, BATCH), dim3(256), 0, stream>>>(k, v, khi, klo, vf);
    attn_kernel<<<dim3(BATCH, N / BM), dim3(256), 0, stream>>>(q, o, khi, klo, vf);
}

// Round 9
// 142.302 us; speedup vs baseline: 1.2072x; 1.0538x over previous
//
#include <hip/hip_runtime.h>

// pixelSNAIL causal attention, MI355X gfx950.
// B=32, N=1024, C=128, CM=256, fp32 in/out.
// softmax over FULL row, strict causal mask, then @V.
// R4: prep_kernel: coalesced global IO + LDS transpose (XOR-swizzled slots).
// R5: swapped QK^T (mfma(K,Q)) -> P lane-local; in-register P->A-frag via
//     cvt_pk_bf16 + permlane32/16_swap; K and V double-buffered, counted
//     vmcnt schedule.  [58.8 us verified — schedule frozen since]
// R6-R11 (all reverted): tiling/occupancy/barrier restructurings -> worse.
// R12: precision re-engineering at FROZEN R5 schedule:
//     QK^T bf16x3 -> f16x2. K stored as single f16 (11-bit mantissa);
//     Q split f16 hi + lo with lo PRE-SCALED x2048 (keeps Qlo in f16
//     normal range; MFMA may flush f16 subnormals). s = a0 + a1/2048.
//     Dropped (K - f16(K))*Q term: max score error ~0.01 -> absmax
//     ~0.04-0.06 (threshold 0.1). Per wave per tile: K LDS reads 16->8
//     b128, QK^T MFMA 24->16, K staging halved, klo workspace deleted,
//     LDS 64->48 KB. PV path (bf16, verified) untouched.

typedef __attribute__((ext_vector_type(8))) short short8;
typedef __attribute__((ext_vector_type(8))) _Float16 half8;
typedef __attribute__((ext_vector_type(4))) float floatx4;

#define MFMA16B(a, b, c) __builtin_amdgcn_mfma_f32_16x16x32_bf16((a), (b), (c), 0, 0, 0)
#define MFMA16H(a, b, c) __builtin_amdgcn_mfma_f32_16x16x32_f16((a), (b), (c), 0, 0, 0)

constexpr int N = 1024, C = 128, CM = 256, BATCH = 32;
constexpr int BM = 64;             // q rows per block (4 waves x 16 rows)
constexpr int BN = 32;             // keys per tile
constexpr int NT = N / BN;         // 32 tiles
constexpr int KFRAG = BN * C;      // 4096 f16 per K tile
constexpr int VFRAG = BN * CM;     // 8192 bf16 per V tile

__device__ __forceinline__ unsigned short f2bf(float x) {
    unsigned int u = __float_as_uint(x);
    u += 0x7fffu + ((u >> 16) & 1u);   // RNE
    return (unsigned short)(u >> 16);
}
__device__ __forceinline__ unsigned short f2h(float x) {
    _Float16 h = (_Float16)x;          // RNE
    union { _Float16 f; unsigned short u; } c;
    c.f = h;
    return c.u;
}
__device__ __forceinline__ uint2 pack4(const unsigned short* s) {
    uint2 u;
    u.x = (unsigned)s[0] | ((unsigned)s[1] << 16);
    u.y = (unsigned)s[2] | ((unsigned)s[3] << 16);
    return u;
}
__device__ __forceinline__ void gl2lds16(const unsigned short* g, unsigned short* l) {
    __builtin_amdgcn_global_load_lds(
        (const __attribute__((address_space(1))) void*)g,
        (__attribute__((address_space(3))) void*)l, 16, 0, 0);
}

// ---------------- prepass: coalesced global IO, LDS transpose ----------------
// Output layouts (consumed by attn_kernel):
//  khi chunk ch in [0,512):  rr=ch&15, qq=(ch>>4)&3, ks=(ch>>6)&3, t=ch>>8
//    khb[ch*8+j] = f16(K[n0 + t*16 + rr][ks*32 + qq*8 + j])
//  vf chunk ch in [0,1024):  rr=ch&15, qq=(ch>>4)&3, ct=ch>>6
//    vfb[ch*8+j] = bf16(V[n0 + qq*8 + j][ct*16 + rr])
__global__ __launch_bounds__(256, 4)
void prep_kernel(const float* __restrict__ kg, const float* __restrict__ vg,
                 unsigned short* __restrict__ khi, unsigned short* __restrict__ vf)
{
    __shared__ __align__(16) unsigned short sKh[KFRAG];   // 8 KB
    __shared__ __align__(16) unsigned short sV[VFRAG];    // 16 KB

    const int tid = threadIdx.x;
    const int l = tid & 63, w = tid >> 6;
    const int tile = blockIdx.x, bat = blockIdx.y;
    const int n0 = tile * BN;
    const float* kb = kg + ((size_t)bat * N + n0) * C;
    const float* vb = vg + ((size_t)bat * N + n0) * CM;

    // ---- K staging: contiguous float4 reads (1 KB/instr/wave), f16 ----
#pragma unroll
    for (int it = 0; it < 4; ++it) {
        const int lin = tid + it * 256;
        const float4 x = *(const float4*)(kb + (size_t)lin * 4);
        const int cr = lin >> 1, h = lin & 1;
        const int slot = cr ^ ((cr >> 4) & 7);
        float xs[4] = {x.x, x.y, x.z, x.w};
        unsigned short hi[4];
#pragma unroll
        for (int e = 0; e < 4; ++e) hi[e] = f2h(xs[e]);
        *(uint2*)(&sKh[slot * 8 + h * 4]) = pack4(hi);
    }

    // ---- V staging: 4 contiguous row-segment float4 reads per group ----
#pragma unroll
    for (int g = 0; g < 2; ++g) {
        const int k0 = g * 16 + w * 4;
        float xa[4][4];   // [e][d] = V[k0+d][4l+e]
#pragma unroll
        for (int d = 0; d < 4; ++d) {
            const float4 t = *(const float4*)(vb + (size_t)(k0 + d) * CM + l * 4);
            xa[0][d] = t.x; xa[1][d] = t.y; xa[2][d] = t.z; xa[3][d] = t.w;
        }
        const int qq = k0 >> 3, j0 = k0 & 7;
#pragma unroll
        for (int e = 0; e < 4; ++e) {
            const int cm = l * 4 + e;
            const int ct = cm >> 4, rr = cm & 15;
            const int ch = ct * 64 + qq * 16 + rr;
            const int slot = ch ^ ((ch >> 6) & 15);
            unsigned short o[4];
#pragma unroll
            for (int d = 0; d < 4; ++d) o[d] = f2bf(xa[e][d]);
            *(uint2*)(&sV[slot * 8 + j0]) = pack4(o);
        }
    }

    __syncthreads();

    unsigned short* khb = khi + ((size_t)bat * NT + tile) * KFRAG;
    unsigned short* vfb = vf + ((size_t)bat * NT + tile) * VFRAG;

    // ---- K out: linear b128 LDS reads, coalesced 16 B/lane global stores ----
#pragma unroll
    for (int it = 0; it < 2; ++it) {
        const int oc = tid + it * 256;
        const int cr = ((oc & 15) + ((oc >> 8) << 4)) * 16 + ((oc >> 6) & 3) * 4 + ((oc >> 4) & 3);
        const int slot = cr ^ ((cr >> 4) & 7);
        *(uint4*)(khb + (size_t)oc * 8) = *(const uint4*)(&sKh[slot * 8]);
    }
    // ---- V out ----
#pragma unroll
    for (int it = 0; it < 4; ++it) {
        const int oc = tid + it * 256;
        const int slot = oc ^ ((oc >> 6) & 15);
        *(uint4*)(vfb + (size_t)oc * 8) = *(const uint4*)(&sV[slot * 8]);
    }
}

// ---------------- main attention kernel ----------------
__global__ __launch_bounds__(256, 2)
void attn_kernel(const float* __restrict__ qg, float* __restrict__ og,
                 const unsigned short* __restrict__ khi,
                 const unsigned short* __restrict__ vf)
{
    __shared__ __align__(16) unsigned short sKhi[2][KFRAG];  // 16 KB dbuf (f16)
    __shared__ __align__(16) unsigned short sV[2][VFRAG];    // 32 KB dbuf (bf16)

    const int tid = threadIdx.x;
    const int w = tid >> 6, ln = tid & 63;
    const int r = ln & 15, qd = ln >> 4;
    const int bat = blockIdx.x;   // batch on x: linear%8 = bat%8 -> same XCD per batch
    const int qt = blockIdx.y;
    const int q0 = qt * BM;

    const float* qb = qg + (size_t)bat * N * C;
    float* ob = og + (size_t)bat * N * CM;
    const unsigned short* khb = khi + (size_t)bat * NT * KFRAG;
    const unsigned short* vfb = vf + (size_t)bat * NT * VFRAG;

    // Q fragments for this wave's 16 rows (q0 + w*16 + r):
    // f16 hi + f16 lo, lo pre-scaled x2048 to stay in f16 normal range.
    half8 qhi[4], qlo[4];
    {
        const float* qr = qb + (size_t)(q0 + w * 16 + r) * C + qd * 8;
#pragma unroll
        for (int ks = 0; ks < 4; ++ks) {
            float4 a = *(const float4*)(qr + ks * 32);
            float4 b = *(const float4*)(qr + ks * 32 + 4);
            float xs[8] = {a.x, a.y, a.z, a.w, b.x, b.y, b.z, b.w};
            half8 h, l;
#pragma unroll
            for (int j = 0; j < 8; ++j) {
                _Float16 hv = (_Float16)xs[j];
                h[j] = hv;
                l[j] = (_Float16)((xs[j] - (float)hv) * 2048.0f);
            }
            qhi[ks] = h;
            qlo[ks] = l;
        }
    }

    floatx4 oacc[16];
#pragma unroll
    for (int ct = 0; ct < 16; ++ct) oacc[ct] = (floatx4){0.f, 0.f, 0.f, 0.f};
    float lsum = 0.f;                       // this lane's q-row partial denom
    const int qrow = q0 + w * 16 + r;       // swapped-QK^T: lane owns ONE q-row

    // prologue: prefetch K(0) + V(0) into buffer 0 (6 loads/thread)
    gl2lds16(khb + (size_t)tid * 8,         &sKhi[0][tid * 8]);
    gl2lds16(khb + (size_t)(tid + 256) * 8, &sKhi[0][(tid + 256) * 8]);
#pragma unroll
    for (int i = 0; i < 4; ++i)
        gl2lds16(vfb + (size_t)(tid + i * 256) * 8, &sV[0][(tid + i * 256) * 8]);

    for (int tile = 0; tile < NT; ++tile) {
        const bool pvt = (tile <= 2 * qt + 1);   // tile holds keys < some row in block
        const int cb = tile & 1;

        // prefetch K(t+1) (+ V(t+1) if needed) into the other buffers; the
        // counted vmcnt leaves exactly the just-issued loads in flight.
        // In-flight bookkeeping: pvt iter issues 6 (2 K + 4 V), else 2.
        if (tile + 1 < NT) {
            const unsigned short* k1 = khb + (size_t)(tile + 1) * KFRAG;
            unsigned short* dh = &sKhi[cb ^ 1][0];
            gl2lds16(k1 + (size_t)tid * 8,         dh + tid * 8);
            gl2lds16(k1 + (size_t)(tid + 256) * 8, dh + (tid + 256) * 8);
            if (tile + 1 <= 2 * qt + 1) {        // V(t+1) needed
                const unsigned short* vs = vfb + (size_t)(tile + 1) * VFRAG;
                unsigned short* dv = &sV[cb ^ 1][0];
#pragma unroll
                for (int i = 0; i < 4; ++i)
                    gl2lds16(vs + (size_t)(tid + i * 256) * 8, dv + (tid + i * 256) * 8);
                asm volatile("s_waitcnt vmcnt(6)" ::: "memory");   // drain K(t)+V(t)
            } else {
                asm volatile("s_waitcnt vmcnt(2)" ::: "memory");   // drain K(t)(+V(t))
            }
        } else {
            asm volatile("s_waitcnt vmcnt(0)" ::: "memory");
        }
        asm volatile("s_barrier" ::: "memory");   // all waves' K(t)/V(t) staged

        // ---- swapped QK^T f16x2: D[key][qrow], 2 independent chains ----
        float pk[8];
#pragma unroll
        for (int t = 0; t < 2; ++t) {
            floatx4 a0 = (floatx4){0.f, 0.f, 0.f, 0.f};
            floatx4 a1 = (floatx4){0.f, 0.f, 0.f, 0.f};
#pragma unroll
            for (int ks = 0; ks < 4; ++ks) {
                half8 bh = *(const half8*)(&sKhi[cb][(((t * 4 + ks) * 64) + ln) * 8]);
                a0 = MFMA16H(bh, qhi[ks], a0);    // A=K -> rows=keys, cols=qrows
                a1 = MFMA16H(bh, qlo[ks], a1);    // lo chain (x2048)
            }
            const int kbase = tile * BN + t * 16 + qd * 4;
#pragma unroll
            for (int rg = 0; rg < 4; ++rg) {
                float s = a0[rg] + a1[rg] * (1.0f / 2048.0f);
                float p = __expf(s - 40.0f);
                lsum += p;                                  // full-row denominator
                pk[t * 4 + rg] = (kbase + rg < qrow) ? p : 0.0f;  // strict causal
            }
        }

        // ---- PV: P->A-frag built in-register (cvt_pk + permlane swaps) ----
        if (pvt) {
            // w0..w3 = packed bf16 pairs: (t0 k0,k1)(t0 k2,k3)(t1 k0,k1)(t1 k2,k3)
            unsigned int w0, w1, w2, w3;
            asm("v_cvt_pk_bf16_f32 %0, %1, %2" : "=v"(w0) : "v"(pk[0]), "v"(pk[1]));
            asm("v_cvt_pk_bf16_f32 %0, %1, %2" : "=v"(w1) : "v"(pk[2]), "v"(pk[3]));
            asm("v_cvt_pk_bf16_f32 %0, %1, %2" : "=v"(w2) : "v"(pk[4]), "v"(pk[5]));
            asm("v_cvt_pk_bf16_f32 %0, %1, %2" : "=v"(w3) : "v"(pk[6]), "v"(pk[7]));
            // lane group qd needs keys 8qd..8qd+7 of its row r:
            // (o0,o2) = permlane16_swap(permlane32_swap(w0, w2)); same for (w1,w3).
            asm("v_permlane32_swap_b32 %0, %1" : "+v"(w0), "+v"(w2));
            asm("v_permlane16_swap_b32 %0, %1" : "+v"(w0), "+v"(w2));
            asm("v_permlane32_swap_b32 %0, %1" : "+v"(w1), "+v"(w3));
            asm("v_permlane16_swap_b32 %0, %1" : "+v"(w1), "+v"(w3));
            uint4 apu = make_uint4(w0, w1, w2, w3);   // keys (0,1)(2,3)(4,5)(6,7)+8qd
            short8 ap = *(const short8*)&apu;
#pragma unroll
            for (int ct = 0; ct < 16; ++ct) {
                short8 bv = *(const short8*)(&sV[cb][(ct * 64 + ln) * 8]);
                oacc[ct] = MFMA16B(ap, bv, oacc[ct]);
            }
        }
        asm volatile("s_barrier" ::: "memory");   // readers done before next overwrite
    }

    // ---- denominator: reduce across the 4 qd groups (lane owns row r) ----
    float vtot = lsum;
    vtot += __shfl_xor(vtot, 16);
    vtot += __shfl_xor(vtot, 32);
    // vtot = full denom for row (q0 + w*16 + r) on every lane

    // ---- divide + store ----
#pragma unroll
    for (int rg = 0; rg < 4; ++rg) {
        float inv = 1.0f / __shfl(vtot, qd * 4 + rg);   // lane qd*4+rg has row qd*4+rg
        float* orow = ob + (size_t)(q0 + w * 16 + qd * 4 + rg) * CM;
#pragma unroll
        for (int ct = 0; ct < 16; ++ct)
            orow[ct * 16 + r] = oacc[ct][rg] * inv;
    }
}

extern "C" void kernel_launch(void* const* d_in, const int* in_sizes, int n_in,
                              void* d_out, int out_size, void* d_ws, size_t ws_size,
                              hipStream_t stream) {
    const float* q = (const float*)d_in[0];
    const float* k = (const float*)d_in[1];
    const float* v = (const float*)d_in[2];
    float* o = (float*)d_out;
    (void)n_in; (void)in_sizes; (void)out_size; (void)ws_size;

    unsigned short* khi = (unsigned short*)d_ws;                       // 8 MB (f16)
    unsigned short* vf  = khi + (size_t)BATCH * NT * KFRAG;            // 16 MB (bf16)

    prep_kernel<<<dim3(NT, BATCH), dim3(256), 0, stream>>>(k, v, khi, vf);
    attn_kernel<<<dim3(BATCH, N / BM), dim3(256), 0, stream>>>(q, o, khi, vf);
}

// Round 10
// 140.691 us; speedup vs baseline: 1.2210x; 1.0114x over previous
//
#include <hip/hip_runtime.h>

// pixelSNAIL causal attention, MI355X gfx950.
// B=32, N=1024, C=128, CM=256, fp32 in/out.
// softmax over FULL row, strict causal mask, then @V.
// R4: prep_kernel: coalesced global IO + LDS transpose (XOR-swizzled slots).
// R5: swapped QK^T (mfma(K,Q)) -> P lane-local; in-register P->A-frag via
//     cvt_pk_bf16 + permlane32/16_swap; counted-vmcnt prefetch schedule.
// R6-R11 (all reverted): tiling/occupancy/barrier restructurings -> worse.
// R12: QK^T bf16x3 -> f16x2 (K single f16; Q = f16 hi + lo x2048).
//     K LDS reads 16->8, QK^T MFMA 24->16, klo workspace deleted. [52.7 us]
// R13: TRIPLE-buffered K and V, ONE barrier per tile. Writes at iter t go
//     to buf[(t+1)%3]; with one barrier/tile max skew = 1 iter, so live
//     readers touch only buf[t%3], buf[(t-1)%3] -> WAR-safe by construction.
//     Unlike R11, load-issue stays BEFORE the counted drain (the proven
//     R5/R12 ordering); only the end barrier + cb-flip are deleted.
//     Barriers 64->32; LDS 48->72 KB (still 2 blocks/CU).

typedef __attribute__((ext_vector_type(8))) short short8;
typedef __attribute__((ext_vector_type(8))) _Float16 half8;
typedef __attribute__((ext_vector_type(4))) float floatx4;

#define MFMA16B(a, b, c) __builtin_amdgcn_mfma_f32_16x16x32_bf16((a), (b), (c), 0, 0, 0)
#define MFMA16H(a, b, c) __builtin_amdgcn_mfma_f32_16x16x32_f16((a), (b), (c), 0, 0, 0)

constexpr int N = 1024, C = 128, CM = 256, BATCH = 32;
constexpr int BM = 64;             // q rows per block (4 waves x 16 rows)
constexpr int BN = 32;             // keys per tile
constexpr int NT = N / BN;         // 32 tiles
constexpr int KFRAG = BN * C;      // 4096 f16 per K tile
constexpr int VFRAG = BN * CM;     // 8192 bf16 per V tile

__device__ __forceinline__ unsigned short f2bf(float x) {
    unsigned int u = __float_as_uint(x);
    u += 0x7fffu + ((u >> 16) & 1u);   // RNE
    return (unsigned short)(u >> 16);
}
__device__ __forceinline__ unsigned short f2h(float x) {
    _Float16 h = (_Float16)x;          // RNE
    union { _Float16 f; unsigned short u; } c;
    c.f = h;
    return c.u;
}
__device__ __forceinline__ uint2 pack4(const unsigned short* s) {
    uint2 u;
    u.x = (unsigned)s[0] | ((unsigned)s[1] << 16);
    u.y = (unsigned)s[2] | ((unsigned)s[3] << 16);
    return u;
}
__device__ __forceinline__ void gl2lds16(const unsigned short* g, unsigned short* l) {
    __builtin_amdgcn_global_load_lds(
        (const __attribute__((address_space(1))) void*)g,
        (__attribute__((address_space(3))) void*)l, 16, 0, 0);
}

// ---------------- prepass: coalesced global IO, LDS transpose ----------------
// Output layouts (consumed by attn_kernel):
//  khi chunk ch in [0,512):  rr=ch&15, qq=(ch>>4)&3, ks=(ch>>6)&3, t=ch>>8
//    khb[ch*8+j] = f16(K[n0 + t*16 + rr][ks*32 + qq*8 + j])
//  vf chunk ch in [0,1024):  rr=ch&15, qq=(ch>>4)&3, ct=ch>>6
//    vfb[ch*8+j] = bf16(V[n0 + qq*8 + j][ct*16 + rr])
__global__ __launch_bounds__(256, 4)
void prep_kernel(const float* __restrict__ kg, const float* __restrict__ vg,
                 unsigned short* __restrict__ khi, unsigned short* __restrict__ vf)
{
    __shared__ __align__(16) unsigned short sKh[KFRAG];   // 8 KB
    __shared__ __align__(16) unsigned short sV[VFRAG];    // 16 KB

    const int tid = threadIdx.x;
    const int l = tid & 63, w = tid >> 6;
    const int tile = blockIdx.x, bat = blockIdx.y;
    const int n0 = tile * BN;
    const float* kb = kg + ((size_t)bat * N + n0) * C;
    const float* vb = vg + ((size_t)bat * N + n0) * CM;

    // ---- K staging: contiguous float4 reads (1 KB/instr/wave), f16 ----
#pragma unroll
    for (int it = 0; it < 4; ++it) {
        const int lin = tid + it * 256;
        const float4 x = *(const float4*)(kb + (size_t)lin * 4);
        const int cr = lin >> 1, h = lin & 1;
        const int slot = cr ^ ((cr >> 4) & 7);
        float xs[4] = {x.x, x.y, x.z, x.w};
        unsigned short hi[4];
#pragma unroll
        for (int e = 0; e < 4; ++e) hi[e] = f2h(xs[e]);
        *(uint2*)(&sKh[slot * 8 + h * 4]) = pack4(hi);
    }

    // ---- V staging: 4 contiguous row-segment float4 reads per group ----
#pragma unroll
    for (int g = 0; g < 2; ++g) {
        const int k0 = g * 16 + w * 4;
        float xa[4][4];   // [e][d] = V[k0+d][4l+e]
#pragma unroll
        for (int d = 0; d < 4; ++d) {
            const float4 t = *(const float4*)(vb + (size_t)(k0 + d) * CM + l * 4);
            xa[0][d] = t.x; xa[1][d] = t.y; xa[2][d] = t.z; xa[3][d] = t.w;
        }
        const int qq = k0 >> 3, j0 = k0 & 7;
#pragma unroll
        for (int e = 0; e < 4; ++e) {
            const int cm = l * 4 + e;
            const int ct = cm >> 4, rr = cm & 15;
            const int ch = ct * 64 + qq * 16 + rr;
            const int slot = ch ^ ((ch >> 6) & 15);
            unsigned short o[4];
#pragma unroll
            for (int d = 0; d < 4; ++d) o[d] = f2bf(xa[e][d]);
            *(uint2*)(&sV[slot * 8 + j0]) = pack4(o);
        }
    }

    __syncthreads();

    unsigned short* khb = khi + ((size_t)bat * NT + tile) * KFRAG;
    unsigned short* vfb = vf + ((size_t)bat * NT + tile) * VFRAG;

    // ---- K out: linear b128 LDS reads, coalesced 16 B/lane global stores ----
#pragma unroll
    for (int it = 0; it < 2; ++it) {
        const int oc = tid + it * 256;
        const int cr = ((oc & 15) + ((oc >> 8) << 4)) * 16 + ((oc >> 6) & 3) * 4 + ((oc >> 4) & 3);
        const int slot = cr ^ ((cr >> 4) & 7);
        *(uint4*)(khb + (size_t)oc * 8) = *(const uint4*)(&sKh[slot * 8]);
    }
    // ---- V out ----
#pragma unroll
    for (int it = 0; it < 4; ++it) {
        const int oc = tid + it * 256;
        const int slot = oc ^ ((oc >> 6) & 15);
        *(uint4*)(vfb + (size_t)oc * 8) = *(const uint4*)(&sV[slot * 8]);
    }
}

// ---------------- main attention kernel ----------------
__global__ __launch_bounds__(256, 2)
void attn_kernel(const float* __restrict__ qg, float* __restrict__ og,
                 const unsigned short* __restrict__ khi,
                 const unsigned short* __restrict__ vf)
{
    __shared__ __align__(16) unsigned short sKhi[3][KFRAG];  // 24 KB tbuf (f16)
    __shared__ __align__(16) unsigned short sV[3][VFRAG];    // 48 KB tbuf (bf16)

    const int tid = threadIdx.x;
    const int w = tid >> 6, ln = tid & 63;
    const int r = ln & 15, qd = ln >> 4;
    const int bat = blockIdx.x;   // batch on x: linear%8 = bat%8 -> same XCD per batch
    const int qt = blockIdx.y;
    const int q0 = qt * BM;

    const float* qb = qg + (size_t)bat * N * C;
    float* ob = og + (size_t)bat * N * CM;
    const unsigned short* khb = khi + (size_t)bat * NT * KFRAG;
    const unsigned short* vfb = vf + (size_t)bat * NT * VFRAG;

    // Q fragments for this wave's 16 rows (q0 + w*16 + r):
    // f16 hi + f16 lo, lo pre-scaled x2048 to stay in f16 normal range.
    half8 qhi[4], qlo[4];
    {
        const float* qr = qb + (size_t)(q0 + w * 16 + r) * C + qd * 8;
#pragma unroll
        for (int ks = 0; ks < 4; ++ks) {
            float4 a = *(const float4*)(qr + ks * 32);
            float4 b = *(const float4*)(qr + ks * 32 + 4);
            float xs[8] = {a.x, a.y, a.z, a.w, b.x, b.y, b.z, b.w};
            half8 h, l;
#pragma unroll
            for (int j = 0; j < 8; ++j) {
                _Float16 hv = (_Float16)xs[j];
                h[j] = hv;
                l[j] = (_Float16)((xs[j] - (float)hv) * 2048.0f);
            }
            qhi[ks] = h;
            qlo[ks] = l;
        }
    }

    floatx4 oacc[16];
#pragma unroll
    for (int ct = 0; ct < 16; ++ct) oacc[ct] = (floatx4){0.f, 0.f, 0.f, 0.f};
    float lsum = 0.f;                       // this lane's q-row partial denom
    const int qrow = q0 + w * 16 + r;       // swapped-QK^T: lane owns ONE q-row

    // prologue: prefetch K(0) + V(0) into buffer 0 (6 loads/thread)
    gl2lds16(khb + (size_t)tid * 8,         &sKhi[0][tid * 8]);
    gl2lds16(khb + (size_t)(tid + 256) * 8, &sKhi[0][(tid + 256) * 8]);
#pragma unroll
    for (int i = 0; i < 4; ++i)
        gl2lds16(vfb + (size_t)(tid + i * 256) * 8, &sV[0][(tid + i * 256) * 8]);

    int cb = 0;
    for (int tile = 0; tile < NT; ++tile) {
        const bool pvt = (tile <= 2 * qt + 1);   // tile holds keys < some row in block
        const int nb = (cb == 2) ? 0 : cb + 1;   // write target: never a live read buf

        // prefetch K(t+1) (+ V(t+1) if needed) into buffer nb; counted vmcnt
        // leaves exactly the just-issued loads in flight across the barrier.
        // WAR-safe without an end barrier: skew <= 1 iter => readers touch
        // only buf[t%3], buf[(t-1)%3]; nb = (t+1)%3 differs from both.
        if (tile + 1 < NT) {
            const unsigned short* k1 = khb + (size_t)(tile + 1) * KFRAG;
            unsigned short* dh = &sKhi[nb][0];
            gl2lds16(k1 + (size_t)tid * 8,         dh + tid * 8);
            gl2lds16(k1 + (size_t)(tid + 256) * 8, dh + (tid + 256) * 8);
            if (tile + 1 <= 2 * qt + 1) {        // V(t+1) needed
                const unsigned short* vs = vfb + (size_t)(tile + 1) * VFRAG;
                unsigned short* dv = &sV[nb][0];
#pragma unroll
                for (int i = 0; i < 4; ++i)
                    gl2lds16(vs + (size_t)(tid + i * 256) * 8, dv + (tid + i * 256) * 8);
                asm volatile("s_waitcnt vmcnt(6)" ::: "memory");   // drain K(t)+V(t)
            } else {
                asm volatile("s_waitcnt vmcnt(2)" ::: "memory");   // drain K(t)(+V(t))
            }
        } else {
            asm volatile("s_waitcnt vmcnt(0)" ::: "memory");
        }
        asm volatile("s_barrier" ::: "memory");   // all waves' K(t)/V(t) staged

        // ---- swapped QK^T f16x2: D[key][qrow], 2 independent chains ----
        float pk[8];
#pragma unroll
        for (int t = 0; t < 2; ++t) {
            floatx4 a0 = (floatx4){0.f, 0.f, 0.f, 0.f};
            floatx4 a1 = (floatx4){0.f, 0.f, 0.f, 0.f};
#pragma unroll
            for (int ks = 0; ks < 4; ++ks) {
                half8 bh = *(const half8*)(&sKhi[cb][(((t * 4 + ks) * 64) + ln) * 8]);
                a0 = MFMA16H(bh, qhi[ks], a0);    // A=K -> rows=keys, cols=qrows
                a1 = MFMA16H(bh, qlo[ks], a1);    // lo chain (x2048)
            }
            const int kbase = tile * BN + t * 16 + qd * 4;
#pragma unroll
            for (int rg = 0; rg < 4; ++rg) {
                float s = a0[rg] + a1[rg] * (1.0f / 2048.0f);
                float p = __expf(s - 40.0f);
                lsum += p;                                  // full-row denominator
                pk[t * 4 + rg] = (kbase + rg < qrow) ? p : 0.0f;  // strict causal
            }
        }

        // ---- PV: P->A-frag built in-register (cvt_pk + permlane swaps) ----
        if (pvt) {
            // w0..w3 = packed bf16 pairs: (t0 k0,k1)(t0 k2,k3)(t1 k0,k1)(t1 k2,k3)
            unsigned int w0, w1, w2, w3;
            asm("v_cvt_pk_bf16_f32 %0, %1, %2" : "=v"(w0) : "v"(pk[0]), "v"(pk[1]));
            asm("v_cvt_pk_bf16_f32 %0, %1, %2" : "=v"(w1) : "v"(pk[2]), "v"(pk[3]));
            asm("v_cvt_pk_bf16_f32 %0, %1, %2" : "=v"(w2) : "v"(pk[4]), "v"(pk[5]));
            asm("v_cvt_pk_bf16_f32 %0, %1, %2" : "=v"(w3) : "v"(pk[6]), "v"(pk[7]));
            // lane group qd needs keys 8qd..8qd+7 of its row r:
            // (o0,o2) = permlane16_swap(permlane32_swap(w0, w2)); same for (w1,w3).
            asm("v_permlane32_swap_b32 %0, %1" : "+v"(w0), "+v"(w2));
            asm("v_permlane16_swap_b32 %0, %1" : "+v"(w0), "+v"(w2));
            asm("v_permlane32_swap_b32 %0, %1" : "+v"(w1), "+v"(w3));
            asm("v_permlane16_swap_b32 %0, %1" : "+v"(w1), "+v"(w3));
            uint4 apu = make_uint4(w0, w1, w2, w3);   // keys (0,1)(2,3)(4,5)(6,7)+8qd
            short8 ap = *(const short8*)&apu;
#pragma unroll
            for (int ct = 0; ct < 16; ++ct) {
                short8 bv = *(const short8*)(&sV[cb][(ct * 64 + ln) * 8]);
                oacc[ct] = MFMA16B(ap, bv, oacc[ct]);
            }
        }
        cb = nb;   // no end barrier: WAR safety from triple buffering
    }

    // ---- denominator: reduce across the 4 qd groups (lane owns row r) ----
    float vtot = lsum;
    vtot += __shfl_xor(vtot, 16);
    vtot += __shfl_xor(vtot, 32);
    // vtot = full denom for row (q0 + w*16 + r) on every lane

    // ---- divide + store ----
#pragma unroll
    for (int rg = 0; rg < 4; ++rg) {
        float inv = 1.0f / __shfl(vtot, qd * 4 + rg);   // lane qd*4+rg has row qd*4+rg
        float* orow = ob + (size_t)(q0 + w * 16 + qd * 4 + rg) * CM;
#pragma unroll
        for (int ct = 0; ct < 16; ++ct)
            orow[ct * 16 + r] = oacc[ct][rg] * inv;
    }
}

extern "C" void kernel_launch(void* const* d_in, const int* in_sizes, int n_in,
                              void* d_out, int out_size, void* d_ws, size_t ws_size,
                              hipStream_t stream) {
    const float* q = (const float*)d_in[0];
    const float* k = (const float*)d_in[1];
    const float* v = (const float*)d_in[2];
    float* o = (float*)d_out;
    (void)n_in; (void)in_sizes; (void)out_size; (void)ws_size;

    unsigned short* khi = (unsigned short*)d_ws;                       // 8 MB (f16)
    unsigned short* vf  = khi + (size_t)BATCH * NT * KFRAG;            // 16 MB (bf16)

    prep_kernel<<<dim3(NT, BATCH), dim3(256), 0, stream>>>(k, v, khi, vf);
    attn_kernel<<<dim3(BATCH, N / BM), dim3(256), 0, stream>>>(q, o, khi, vf);
}